// Round 8
// baseline (443.817 us; speedup 1.0000x reference)
//
#include <hip/hip_runtime.h>
#include <hip/hip_fp16.h>

#define N_NODES 100000
#define N_GRAPHS 64
#define BN_EPS 1e-5
#define NSB 98   // ceil(N_NODES / 1024) scan blocks

typedef _Float16 f16x8 __attribute__((ext_vector_type(8)));
typedef float f32x4 __attribute__((ext_vector_type(4)));

union F16x8u {
    f16x8 v;
    __half2 h2[4];
    uint4 u;
};

__device__ __forceinline__ float bfly64(float v) {
#pragma unroll
    for (int m = 1; m < 64; m <<= 1) v += __shfl_xor(v, m, 64);
    return v;
}

__device__ __forceinline__ unsigned pack_h2(float a, float b) {
    __half2 h = __floats2half2_rn(a, b);
    unsigned w;
    __builtin_memcpy(&w, &h, 4);
    return w;
}

__device__ __forceinline__ float2 unpack_h2(unsigned w) {
    __half2 h;
    __builtin_memcpy(&h, &w, 4);
    return __half22float2(h);
}

// ---------------- CSR build pass 1: per-node degree count ----------------
__global__ __launch_bounds__(256)
void deg_count(const int* __restrict__ dst, int* __restrict__ deg, int E) {
    int stride = gridDim.x * 256;
    for (int e = blockIdx.x * 256 + threadIdx.x; e < E; e += stride) {
        int d = __builtin_nontemporal_load(dst + e);
        atomicAdd(&deg[d], 1);
    }
}

// ---------------- CSR build pass 2a: per-1024-chunk degree sums ----------------
__global__ __launch_bounds__(256)
void scan_a(const int* __restrict__ deg, int* __restrict__ bsum, int N) {
    __shared__ int ws[4];
    int tid = threadIdx.x;
    int i0 = blockIdx.x * 1024 + tid * 4;
    int s = 0;
    if (i0 < N) {            // N % 4 == 0 -> quad fully in-range
        int4 v = *(const int4*)(deg + i0);
        s = v.x + v.y + v.z + v.w;
    }
    for (int m = 1; m < 64; m <<= 1) s += __shfl_xor(s, m, 64);
    if ((tid & 63) == 0) ws[tid >> 6] = s;
    __syncthreads();
    if (tid == 0) bsum[blockIdx.x] = ws[0] + ws[1] + ws[2] + ws[3];
}

// ---------------- CSR build pass 2b: scan chunk sums (1 block) ----------------
__global__ void scan_b(const int* __restrict__ bsum, int* __restrict__ bbase) {
    __shared__ int sh[128];
    int t = threadIdx.x;
    sh[t] = (t < NSB) ? bsum[t] : 0;
    __syncthreads();
    for (int st = 1; st < 128; st <<= 1) {
        int v = (t >= st) ? sh[t - st] : 0;
        __syncthreads();
        sh[t] += v;
        __syncthreads();
    }
    if (t < NSB) bbase[t] = t ? sh[t - 1] : 0;
}

// ---------------- CSR build pass 2c: write offs + cursors ----------------
__global__ __launch_bounds__(256)
void scan_c(const int* __restrict__ deg, const int* __restrict__ bbase,
            int* __restrict__ offs, int* __restrict__ cur, int N, int E) {
    __shared__ int sh[256];
    int tid = threadIdx.x;
    int i0 = blockIdx.x * 1024 + tid * 4;
    int d0 = 0, d1 = 0, d2 = 0, d3 = 0;
    if (i0 < N) {
        int4 v = *(const int4*)(deg + i0);
        d0 = v.x; d1 = v.y; d2 = v.z; d3 = v.w;
    }
    int t3 = d0 + d1 + d2 + d3;
    sh[tid] = t3;
    __syncthreads();
    for (int st = 1; st < 256; st <<= 1) {
        int v = (tid >= st) ? sh[tid - st] : 0;
        __syncthreads();
        sh[tid] += v;
        __syncthreads();
    }
    int ex = bbase[blockIdx.x] + (tid ? sh[tid - 1] : 0);
    if (i0 < N) {
        int4 o;
        o.x = ex; o.y = ex + d0; o.z = ex + d0 + d1; o.w = ex + d0 + d1 + d2;
        *(int4*)(offs + i0) = o;
        *(int4*)(cur + i0) = o;
        if (i0 + 4 == N) offs[N] = ex + t3;   // == E
    }
    (void)E;
}

// ---------------- CSR build pass 3: cursor scatter ----------------
__global__ __launch_bounds__(256)
void scatter(const int* __restrict__ dst, const int* __restrict__ src,
             int* __restrict__ cur, int* __restrict__ nbr, int E) {
    int stride = gridDim.x * 256;
    for (int e = blockIdx.x * 256 + threadIdx.x; e < E; e += stride) {
        int d = __builtin_nontemporal_load(dst + e);
        int s = __builtin_nontemporal_load(src + e);
        int p = atomicAdd(&cur[d], 1);
        nbr[p] = s;
    }
}

// ---------------- layer 1 fused: agg + linear + BN stats; fp16 h1 out ----------------
__global__ __launch_bounds__(256)
void layer1_fused(const float2* __restrict__ x2,
                  const int* __restrict__ offs, const int* __restrict__ nbr,
                  const float* __restrict__ Wl, const float* __restrict__ bl,
                  const float* __restrict__ Wr,
                  __half* __restrict__ hout16,
                  double* __restrict__ sums, int N) {
    __shared__ float sAr[64];
    int tid = threadIdx.x;
    if (tid < 64) sAr[tid] = 0.f;
    __syncthreads();
    int n = blockIdx.x * 256 + tid;
    bool valid = (n < N);
    int beg = 0, end = 0;
    if (valid) { beg = offs[n]; end = offs[n + 1]; }
    float ax0 = 0.f, ay0 = 0.f, ax1 = 0.f, ay1 = 0.f;
    int j = beg;
    // 16-deep gather: 16 independent loads in flight (x table is L2-resident)
    for (; j + 16 <= end; j += 16) {
        int s[16];
#pragma unroll
        for (int u = 0; u < 16; ++u) s[u] = __builtin_nontemporal_load(nbr + j + u);
        float2 v[16];
#pragma unroll
        for (int u = 0; u < 16; ++u) v[u] = x2[s[u]];
#pragma unroll
        for (int u = 0; u < 16; ++u) {
            if (u & 1) { ax1 += v[u].x; ay1 += v[u].y; }
            else       { ax0 += v[u].x; ay0 += v[u].y; }
        }
    }
    for (; j + 4 <= end; j += 4) {
        int s[4];
#pragma unroll
        for (int u = 0; u < 4; ++u) s[u] = __builtin_nontemporal_load(nbr + j + u);
        float2 v[4];
#pragma unroll
        for (int u = 0; u < 4; ++u) v[u] = x2[s[u]];
        ax0 += v[0].x; ay0 += v[0].y;
        ax1 += v[1].x; ay1 += v[1].y;
        ax0 += v[2].x; ay0 += v[2].y;
        ax1 += v[3].x; ay1 += v[3].y;
    }
    for (; j < end; ++j) {
        float2 v = x2[nbr[j]];
        ax0 += v.x; ay0 += v.y;
    }
    float invd = 1.0f / fmaxf((float)(end - beg), 1.0f);
    float a0 = (ax0 + ax1) * invd, a1 = (ay0 + ay1) * invd;
    float x0 = 0.f, x1 = 0.f;
    if (valid) {
        float2 xv = x2[n];
        x0 = xv.x; x1 = xv.y;
    }
    float acc[32];
#pragma unroll
    for (int jj = 0; jj < 32; ++jj)
        acc[jj] = bl[jj] + a0 * Wl[jj] + a1 * Wl[32 + jj] + x0 * Wr[jj] + x1 * Wr[32 + jj];
    if (valid) {
        unsigned w[16];
#pragma unroll
        for (int p = 0; p < 16; ++p) w[p] = pack_h2(acc[2*p], acc[2*p+1]);
        uint4* q = (uint4*)(hout16 + (size_t)n * 32);
        q[0] = make_uint4(w[0], w[1], w[2], w[3]);
        q[1] = make_uint4(w[4], w[5], w[6], w[7]);
        q[2] = make_uint4(w[8], w[9], w[10], w[11]);
        q[3] = make_uint4(w[12], w[13], w[14], w[15]);
    }
    int lane = tid & 63;
#pragma unroll
    for (int jj = 0; jj < 32; ++jj) {
        float v = valid ? acc[jj] : 0.f;
        float s = bfly64(v);
        float q = bfly64(v * v);
        if (lane == jj) atomicAdd(&sAr[jj], s);
        if (lane == 32 + jj) atomicAdd(&sAr[32 + jj], q);
    }
    __syncthreads();
    if (tid < 64) atomicAdd(&sums[tid], (double)sAr[tid]);
}

// ---------------- per-node BN+ReLU apply: h -> b (fp16), once per node ----------------
template<int F>
__global__ __launch_bounds__(256)
void bn_apply(const uint4* __restrict__ h, const double* __restrict__ sums,
              const float* __restrict__ gamma, const float* __restrict__ beta,
              uint4* __restrict__ out, int N) {
    __shared__ __align__(16) float lsc[F], lsf[F];
    int tid = threadIdx.x;
    if (tid < F) {
        double mu = sums[tid] / (double)N_NODES;
        double var = sums[F + tid] / (double)N_NODES - mu * mu;
        if (var < 0.0) var = 0.0;
        double sc = (double)gamma[tid] / sqrt(var + BN_EPS);
        lsc[tid] = (float)sc;
        lsf[tid] = (float)((double)beta[tid] - mu * sc);
    }
    __syncthreads();
    constexpr int FV = F / 8;
    int total = N * FV;
    for (int i = blockIdx.x * 256 + tid; i < total; i += gridDim.x * 256) {
        uint4 v = h[i];
        int c4 = (i & (FV - 1)) * 2;      // float4 index of first quad
        float4 sca = ((const float4*)lsc)[c4];
        float4 scb = ((const float4*)lsc)[c4 + 1];
        float4 sfa = ((const float4*)lsf)[c4];
        float4 sfb = ((const float4*)lsf)[c4 + 1];
        float2 f0 = unpack_h2(v.x), f1 = unpack_h2(v.y);
        float2 f2 = unpack_h2(v.z), f3 = unpack_h2(v.w);
        uint4 o;
        o.x = pack_h2(fmaxf(f0.x * sca.x + sfa.x, 0.f), fmaxf(f0.y * sca.y + sfa.y, 0.f));
        o.y = pack_h2(fmaxf(f1.x * sca.z + sfa.z, 0.f), fmaxf(f1.y * sca.w + sfa.w, 0.f));
        o.z = pack_h2(fmaxf(f2.x * scb.x + sfb.x, 0.f), fmaxf(f2.y * scb.y + sfb.y, 0.f));
        o.w = pack_h2(fmaxf(f3.x * scb.z + sfb.z, 0.f), fmaxf(f3.y * scb.w + sfb.w, 0.f));
        out[i] = o;
    }
}

// ---------------- fp16 sum-gather agg, 16-deep MLP, fp32 dual-bank accum ----------------
__device__ __forceinline__ void accum8_h16(float* acc, uint4 v) {
    float2 f0 = unpack_h2(v.x), f1 = unpack_h2(v.y);
    float2 f2 = unpack_h2(v.z), f3 = unpack_h2(v.w);
    acc[0] += f0.x; acc[1] += f0.y; acc[2] += f1.x; acc[3] += f1.y;
    acc[4] += f2.x; acc[5] += f2.y; acc[6] += f3.x; acc[7] += f3.y;
}

template<int F>
__global__ __launch_bounds__(256)
void agg_sum(const uint4* __restrict__ xb, const int* __restrict__ offs,
             const int* __restrict__ nbr, uint4* __restrict__ aggh, int N) {
    constexpr int FV = F / 8;            // uint4 lanes per row
    constexpr int NPB = 256 / FV;        // nodes per block
    int n = blockIdx.x * NPB + threadIdx.y;
    if (n >= N) return;
    int f = threadIdx.x;
    int beg = offs[n], end = offs[n + 1];
    float a0[8], a1[8];
#pragma unroll
    for (int q = 0; q < 8; ++q) { a0[q] = 0.f; a1[q] = 0.f; }
    int j = beg;
    // 16-deep main loop: 16 independent gathers in flight per thread
    for (; j + 16 <= end; j += 16) {
        int s[16];
#pragma unroll
        for (int u = 0; u < 16; ++u) s[u] = __builtin_nontemporal_load(nbr + j + u);
        uint4 v[16];
#pragma unroll
        for (int u = 0; u < 16; ++u) v[u] = xb[s[u] * FV + f];
#pragma unroll
        for (int u = 0; u < 16; ++u)
            accum8_h16((u & 1) ? a1 : a0, v[u]);
    }
    if (j + 8 <= end) {
        int s[8];
#pragma unroll
        for (int u = 0; u < 8; ++u) s[u] = __builtin_nontemporal_load(nbr + j + u);
        uint4 v[8];
#pragma unroll
        for (int u = 0; u < 8; ++u) v[u] = xb[s[u] * FV + f];
#pragma unroll
        for (int u = 0; u < 8; ++u)
            accum8_h16((u & 1) ? a1 : a0, v[u]);
        j += 8;
    }
    if (j + 4 <= end) {
        int s[4];
#pragma unroll
        for (int u = 0; u < 4; ++u) s[u] = __builtin_nontemporal_load(nbr + j + u);
        uint4 v[4];
#pragma unroll
        for (int u = 0; u < 4; ++u) v[u] = xb[s[u] * FV + f];
#pragma unroll
        for (int u = 0; u < 4; ++u)
            accum8_h16((u & 1) ? a1 : a0, v[u]);
        j += 4;
    }
    for (; j < end; ++j) {
        uint4 v = xb[__builtin_nontemporal_load(nbr + j) * FV + f];
        accum8_h16(a0, v);
    }
    float invd = 1.0f / fmaxf((float)(end - beg), 1.0f);
    uint4 o;
    o.x = pack_h2((a0[0] + a1[0]) * invd, (a0[1] + a1[1]) * invd);
    o.y = pack_h2((a0[2] + a1[2]) * invd, (a0[3] + a1[3]) * invd);
    o.z = pack_h2((a0[4] + a1[4]) * invd, (a0[5] + a1[5]) * invd);
    o.w = pack_h2((a0[6] + a1[6]) * invd, (a0[7] + a1[7]) * invd);
    aggh[n * FV + f] = o;
}

// ---------------- weight packing for MFMA: W -> (hi, lo) fp16 fragment order ----------------
// frag[kb][cb][lane][i] holds W[kb*32 + (lane>>4)*8 + i][cb*16 + (lane&15)].
// A-load and B-pack use the SAME (lane,i)->k map; only C/D layout matters (HW-verified).
__global__ __launch_bounds__(256)
void pack_w(const float* __restrict__ Wl2, const float* __restrict__ Wr2,
            const float* __restrict__ Wl3, const float* __restrict__ Wr3,
            __half* __restrict__ pk) {
    int e = blockIdx.x * 256 + threadIdx.x;   // grid is exactly 80*256 = 20480
    const float* W; int le, DOUT, NCB, base, SZ;
    if (e < 2048)       { W = Wl2; le = e;         DOUT = 64;  NCB = 4; base = 0;     SZ = 2048; }
    else if (e < 4096)  { W = Wr2; le = e - 2048;  DOUT = 64;  NCB = 4; base = 4096;  SZ = 2048; }
    else if (e < 12288) { W = Wl3; le = e - 4096;  DOUT = 128; NCB = 8; base = 8192;  SZ = 8192; }
    else                { W = Wr3; le = e - 12288; DOUT = 128; NCB = 8; base = 24576; SZ = 8192; }
    int i = le & 7;
    int lane = (le >> 3) & 63;
    int cbkb = le >> 9;
    int cb = cbkb % NCB;
    int kb = cbkb / NCB;
    int k = kb * 32 + ((lane >> 4) << 3) + i;
    int col = cb * 16 + (lane & 15);
    float w = W[k * DOUT + col];
    __half h = __float2half(w);
    float lo = w - __half2float(h);
    pk[base + le] = h;
    pk[base + SZ + le] = __float2half(lo);
}

// ---------------- MFMA linear: pure-load fp16 fragments (agg pre-scaled, x pre-BN'd),
// split-fp16 weights, fp32 MFMA accumulate, fp16 out, fused BN-stats partials ----------------
template<int DIN, int DOUT>
__global__ __launch_bounds__(256)
void linear_mfma(const __half* __restrict__ bnx16, const __half* __restrict__ agg16,
                 const __half* __restrict__ wlhi, const __half* __restrict__ wllo,
                 const __half* __restrict__ wrhi, const __half* __restrict__ wrlo,
                 const float* __restrict__ bl,
                 __half* __restrict__ hout16, float* __restrict__ partial, int N) {
    constexpr int KB = DIN / 32;    // K-slabs of 32
    constexpr int NCB = DOUT / 16;  // col-blocks of 16
    constexpr int MREP = 2;         // 16-row fragments per wave
    constexpr int MB = 4 * MREP * 16;  // 128 rows per block
    __shared__ float blkS[DOUT], blkQ[DOUT];
    int tid = threadIdx.x;
    for (int i = tid; i < DOUT; i += 256) { blkS[i] = 0.f; blkQ[i] = 0.f; }
    __syncthreads();
    int n0 = blockIdx.x * MB;

    int wave = tid >> 6;
    int lane = tid & 63;
    int rlane = lane & 15;
    int kg = lane >> 4;          // 0..3 -> k-group of 8
    int rbase = n0 + wave * (MREP * 16);

    // ---- A fragments: pure vector loads ----
    f16x8 aA[MREP][KB], aX[MREP][KB];
#pragma unroll
    for (int m = 0; m < MREP; ++m) {
        int row = rbase + m * 16 + rlane;
        int rowc = min(row, N - 1);
#pragma unroll
        for (int kb = 0; kb < KB; ++kb) {
            int c0 = kb * 32 + kg * 8;
            F16x8u ta, tx;
            ta.u = *(const uint4*)(agg16 + (size_t)rowc * DIN + c0);
            tx.u = *(const uint4*)(bnx16 + (size_t)rowc * DIN + c0);
            aA[m][kb] = ta.v;
            aX[m][kb] = tx.v;
        }
    }

    // ---- accumulators init with bias (D layout: row=(lane>>4)*4+r, col=lane&15) ----
    f32x4 acc[MREP][NCB];
#pragma unroll
    for (int cb = 0; cb < NCB; ++cb) {
        float bv = bl[cb * 16 + rlane];
#pragma unroll
        for (int m = 0; m < MREP; ++m)
            acc[m][cb] = {bv, bv, bv, bv};
    }

    // ---- MFMA main: acc += aA*(Wl_hi+Wl_lo) + aX*(Wr_hi+Wr_lo) ----
#pragma unroll
    for (int cb = 0; cb < NCB; ++cb) {
#pragma unroll
        for (int kb = 0; kb < KB; ++kb) {
            size_t fo = ((size_t)(kb * NCB + cb) * 64 + lane) * 8;
            f16x8 blh = *(const f16x8*)(wlhi + fo);
            f16x8 bll = *(const f16x8*)(wllo + fo);
            f16x8 brh = *(const f16x8*)(wrhi + fo);
            f16x8 brl = *(const f16x8*)(wrlo + fo);
#pragma unroll
            for (int m = 0; m < MREP; ++m) {
                acc[m][cb] = __builtin_amdgcn_mfma_f32_16x16x32_f16(aA[m][kb], blh, acc[m][cb], 0, 0, 0);
                acc[m][cb] = __builtin_amdgcn_mfma_f32_16x16x32_f16(aA[m][kb], bll, acc[m][cb], 0, 0, 0);
                acc[m][cb] = __builtin_amdgcn_mfma_f32_16x16x32_f16(aX[m][kb], brh, acc[m][cb], 0, 0, 0);
                acc[m][cb] = __builtin_amdgcn_mfma_f32_16x16x32_f16(aX[m][kb], brl, acc[m][cb], 0, 0, 0);
            }
        }
    }

    // ---- store fp16 outputs ----
#pragma unroll
    for (int m = 0; m < MREP; ++m) {
        int rowb = rbase + m * 16 + kg * 4;
#pragma unroll
        for (int r = 0; r < 4; ++r) {
            int node = rowb + r;
            if (node < N) {
#pragma unroll
                for (int cb = 0; cb < NCB; ++cb)
                    hout16[(size_t)node * DOUT + cb * 16 + rlane] = __float2half(acc[m][cb][r]);
            }
        }
    }

    // ---- fused BN-stats partials: per-block sum/sumsq per feature ----
#pragma unroll
    for (int cb = 0; cb < NCB; ++cb) {
        float s = 0.f, q = 0.f;
#pragma unroll
        for (int m = 0; m < MREP; ++m) {
            int rowb = rbase + m * 16 + kg * 4;
#pragma unroll
            for (int r = 0; r < 4; ++r) {
                if (rowb + r < N) {
                    float v = acc[m][cb][r];
                    s += v; q += v * v;
                }
            }
        }
        s += __shfl_xor(s, 16, 64); s += __shfl_xor(s, 32, 64);
        q += __shfl_xor(q, 16, 64); q += __shfl_xor(q, 32, 64);
        if (kg == 0) {
            atomicAdd(&blkS[cb * 16 + rlane], s);
            atomicAdd(&blkQ[cb * 16 + rlane], q);
        }
    }
    __syncthreads();
    float* po = partial + (size_t)blockIdx.x * (2 * DOUT);
    for (int i = tid; i < DOUT; i += 256) {
        po[i] = blkS[i];
        po[DOUT + i] = blkQ[i];
    }
}

// ---------------- stats finalize: reduce P block-partials per feature in fp64, fixed order ----------------
template<int F>
__global__ __launch_bounds__(256)
void stats_finalize2(const float* __restrict__ partial, double* __restrict__ sums, int P) {
    __shared__ double sh[256];
    int i = blockIdx.x;
    int t = threadIdx.x;
    double a = 0.0;
    for (int k = t; k < P; k += 256)
        a += (double)partial[(size_t)k * (2 * F) + i];
    sh[t] = a;
    __syncthreads();
    for (int st = 128; st > 0; st >>= 1) {
        if (t < st) sh[t] += sh[t + st];
        __syncthreads();
    }
    if (t == 0) sums[i] = sh[0];
}

// ---------------- pool (fp16 h3) with inline BN3 finalize + fused ReLU ----------------
__global__ void pool_partial(const __half* __restrict__ h, const int* __restrict__ batch,
                             const double* __restrict__ sums,
                             const float* __restrict__ gamma, const float* __restrict__ beta,
                             double* __restrict__ pooled_d, int N) {
    __shared__ float lsc[128], lsf[128];
    const int CH = 64;
    int f = threadIdx.x;
    {
        double mu = sums[f] / (double)N_NODES;
        double var = sums[128 + f] / (double)N_NODES - mu * mu;
        if (var < 0.0) var = 0.0;
        double sc = (double)gamma[f] / sqrt(var + BN_EPS);
        lsc[f] = (float)sc;
        lsf[f] = (float)((double)beta[f] - mu * sc);
    }
    __syncthreads();
    int n0 = blockIdx.x * CH;
    if (n0 >= N) return;
    int n1 = min(n0 + CH, N);
    float sc = lsc[f], sf = lsf[f];
    int g = batch[n0];
    float acc = 0.f;
    for (int n = n0; n < n1; ++n) {
        int bg = batch[n];
        if (bg != g) {
            atomicAdd(&pooled_d[g * 128 + f], (double)acc);
            acc = 0.f;
            g = bg;
        }
        float v = __half2float(h[(long long)n * 128 + f]);
        acc += fmaxf(v * sc + sf, 0.f);
    }
    atomicAdd(&pooled_d[g * 128 + f], (double)acc);
}

// ---------------- fused pool-finalize + head MLP ----------------
__global__ void mlp_fused(const double* __restrict__ pooled_d, const int* __restrict__ batch,
                          const float* __restrict__ Wf1, const float* __restrict__ bf1,
                          const float* __restrict__ Wf2, const float* __restrict__ bf2,
                          float* __restrict__ out, int N) {
    __shared__ float sp[128];
    int g = blockIdx.x;
    int t = threadIdx.x;
    int lo = 0, hi = N;
    while (lo < hi) { int m = (lo + hi) >> 1; if (batch[m] < g) lo = m + 1; else hi = m; }
    int start = lo;
    hi = N;
    while (lo < hi) { int m = (lo + hi) >> 1; if (batch[m] < g + 1) lo = m + 1; else hi = m; }
    int cnt = lo - start;
    sp[t] = (float)(pooled_d[g * 128 + t] / (double)max(cnt, 1));
    __syncthreads();
    if (t < 64) {
        float hacc = bf1[t];
#pragma unroll 8
        for (int k = 0; k < 128; ++k) hacc += sp[k] * Wf1[k * 64 + t];
        hacc = fmaxf(hacc, 0.f) * Wf2[t];
        for (int o = 32; o > 0; o >>= 1) hacc += __shfl_down(hacc, o);
        if (t == 0) out[g] = hacc + bf2[0];
    }
}

extern "C" void kernel_launch(void* const* d_in, const int* in_sizes, int n_in,
                              void* d_out, int out_size, void* d_ws, size_t ws_size,
                              hipStream_t stream) {
    const float* x     = (const float*)d_in[0];
    const int*   ei    = (const int*)d_in[1];
    const int*   batch = (const int*)d_in[2];
    const float *Wl1=(const float*)d_in[3],  *bl1=(const float*)d_in[4],  *Wr1=(const float*)d_in[5];
    const float *g1 =(const float*)d_in[6],  *be1=(const float*)d_in[7];
    const float *Wl2=(const float*)d_in[8],  *bl2=(const float*)d_in[9],  *Wr2=(const float*)d_in[10];
    const float *g2 =(const float*)d_in[11], *be2=(const float*)d_in[12];
    const float *Wl3=(const float*)d_in[13], *bl3=(const float*)d_in[14], *Wr3=(const float*)d_in[15];
    const float *g3 =(const float*)d_in[16], *be3=(const float*)d_in[17];
    const float *Wf1=(const float*)d_in[18], *bf1=(const float*)d_in[19];
    const float *Wf2=(const float*)d_in[20], *bf2=(const float*)d_in[21];

    const int N = N_NODES;
    const int E = in_sizes[1] / 2;
    const int* src = ei;
    const int* dst = ei + E;

    char* ws = (char*)d_ws;
    size_t off = 0;
    auto salloc = [&](size_t bytes) {
        void* p = ws + off;
        off += (bytes + 255) & ~(size_t)255;
        return p;
    };
    // --- zero-init region (one memset) ---
    int*    deg     = (int*)   salloc((size_t)N * 4);                // 400 KB
    double* sums    = (double*)salloc(768 * 8);
    double* pooledd = (double*)salloc((size_t)N_GRAPHS * 128 * 8);
    size_t zero_bytes = off;
    // --- rest ---
    int*    offs    = (int*)   salloc((size_t)(N + 4) * 4);
    int*    cur     = (int*)   salloc((size_t)N * 4);
    int*    bsum    = (int*)   salloc(128 * 4);
    int*    bbase   = (int*)   salloc(128 * 4);
    int*    nbr     = (int*)   salloc((size_t)E * 4);
    float*  partial = (float*) salloc((size_t)1024 * 256 * 4);       // 1 MB (stats partials)
    __half* pk      = (__half*)salloc((size_t)40960 * 2);            // 80 KB packed weights
    __half* h1h     = (__half*)salloc((size_t)(N + 256) * 32 * 2);   // 6.4 MB
    __half* b1h     = (__half*)salloc((size_t)(N + 256) * 32 * 2);   // 6.4 MB bnrelu(h1)
    __half* h2h     = (__half*)salloc((size_t)(N + 256) * 64 * 2);   // 12.8 MB
    __half* b2h     = (__half*)salloc((size_t)(N + 256) * 64 * 2);   // 12.8 MB bnrelu(h2)
    __half* h3h     = (__half*)salloc((size_t)(N + 256) * 128 * 2);  // 25.7 MB
    __half* aggh    = (__half*)salloc((size_t)(N + 256) * 64 * 2);   // 12.8 MB
    (void)ws_size;

    double* sums1 = sums, *sums2 = sums + 256, *sums3 = sums + 512;

    const __half *pwl2h = pk,         *pwl2l = pk + 2048;
    const __half *pwr2h = pk + 4096,  *pwr2l = pk + 6144;
    const __half *pwl3h = pk + 8192,  *pwl3l = pk + 16384;
    const __half *pwr3h = pk + 24576, *pwr3l = pk + 32768;

    hipMemsetAsync(deg, 0, zero_bytes, stream);

    // ---- weight packing (tiny; independent of CSR build) ----
    pack_w<<<80, 256, 0, stream>>>(Wl2, Wr2, Wl3, Wr3, pk);

    // ---- CSR build: deg count -> hierarchical scan -> cursor scatter ----
    deg_count<<<1024, 256, 0, stream>>>(dst, deg, E);
    scan_a<<<NSB, 256, 0, stream>>>(deg, bsum, N);
    scan_b<<<1, 128, 0, stream>>>(bsum, bbase);
    scan_c<<<NSB, 256, 0, stream>>>(deg, bbase, offs, cur, N, E);
    scatter<<<1024, 256, 0, stream>>>(dst, src, cur, nbr, E);

    const int NL = (N + 255) / 256;
    const int NBLK = (N + 127) / 128;   // 782 blocks for linear_mfma

    // ---- layer 1: fused agg + linear + stats -> fp16 h1 ----
    layer1_fused<<<NL, 256, 0, stream>>>((const float2*)x, offs, nbr,
                                          Wl1, bl1, Wr1, h1h, sums1, N);

    // ---- layer 2 ----
    bn_apply<32><<<512, 256, 0, stream>>>((const uint4*)h1h, sums1, g1, be1, (uint4*)b1h, N);
    agg_sum<32><<<(N + 63) / 64, dim3(4, 64), 0, stream>>>(
        (const uint4*)b1h, offs, nbr, (uint4*)aggh, N);
    linear_mfma<32, 64><<<NBLK, 256, 0, stream>>>(
        b1h, (const __half*)aggh, pwl2h, pwl2l, pwr2h, pwr2l, bl2, h2h, partial, N);
    stats_finalize2<64><<<128, 256, 0, stream>>>(partial, sums2, NBLK);

    // ---- layer 3 ----
    bn_apply<64><<<512, 256, 0, stream>>>((const uint4*)h2h, sums2, g2, be2, (uint4*)b2h, N);
    agg_sum<64><<<(N + 31) / 32, dim3(8, 32), 0, stream>>>(
        (const uint4*)b2h, offs, nbr, (uint4*)aggh, N);
    linear_mfma<64, 128><<<NBLK, 256, 0, stream>>>(
        b2h, (const __half*)aggh, pwl3h, pwl3l, pwr3h, pwr3l, bl3, h3h, partial, N);
    stats_finalize2<128><<<256, 256, 0, stream>>>(partial, sums3, NBLK);

    // ---- pool + head ----
    pool_partial<<<(N + 63) / 64, 128, 0, stream>>>(h3h, batch, sums3, g3, be3, pooledd, N);
    mlp_fused<<<N_GRAPHS, 128, 0, stream>>>(pooledd, batch, Wf1, bf1, Wf2, bf2, (float*)d_out, N);
}

// Round 10
// 338.366 us; speedup vs baseline: 1.3116x; 1.3116x over previous
//
#include <hip/hip_runtime.h>
#include <hip/hip_fp16.h>

#define N_NODES 100000
#define N_GRAPHS 64
#define BN_EPS 1e-5

#define NB 782
#define NC 49
#define PT1 4096
#define PT2 2048
#define BPC 16
#define CAP 3072

typedef _Float16 f16x8 __attribute__((ext_vector_type(8)));
typedef float f32x4 __attribute__((ext_vector_type(4)));

union F16x8u {
    f16x8 v;
    __half2 h2[4];
    uint4 u;
};

__device__ __forceinline__ float bfly64(float v) {
#pragma unroll
    for (int m = 1; m < 64; m <<= 1) v += __shfl_xor(v, m, 64);
    return v;
}

__device__ __forceinline__ unsigned pack_h2(float a, float b) {
    __half2 h = __floats2half2_rn(a, b);
    unsigned w;
    __builtin_memcpy(&w, &h, 4);
    return w;
}

__device__ __forceinline__ float2 unpack_h2(unsigned w) {
    __half2 h;
    __builtin_memcpy(&h, &w, 4);
    return __half22float2(h);
}

// ---------------- pass 1: fine-bucket histogram ----------------
__global__ void hist_fine(const int* __restrict__ dst, int* __restrict__ bhist, int E) {
    __shared__ int h[NB];
    for (int i = threadIdx.x; i < NB; i += 256) h[i] = 0;
    __syncthreads();
    int stride = gridDim.x * 256;
    for (int e = blockIdx.x * 256 + threadIdx.x; e < E; e += stride) {
        int d = __builtin_nontemporal_load(dst + e);
        atomicAdd(&h[d >> 7], 1);
    }
    __syncthreads();
    for (int i = threadIdx.x; i < NB; i += 256)
        if (h[i]) atomicAdd(&bhist[i], h[i]);
}

// ---------------- pass 2: scan histogram -> offsets & cursors ----------------
__global__ void scan_buckets(const int* __restrict__ bhist, int* __restrict__ bo,
                             int* __restrict__ fcur, int* __restrict__ co,
                             int* __restrict__ ccur) {
    __shared__ int sh[1024];
    int t = threadIdx.x;
    sh[t] = (t < NB) ? bhist[t] : 0;
    __syncthreads();
    for (int st = 1; st < 1024; st <<= 1) {
        int v = (t >= st) ? sh[t - st] : 0;
        __syncthreads();
        sh[t] += v;
        __syncthreads();
    }
    int total = sh[NB - 1];
    if (t < NB) {
        int e = t ? sh[t - 1] : 0;
        bo[t] = e; fcur[t] = e;
    } else if (t < 784) {
        if (t == NB) bo[NB] = total;
        fcur[t] = total;
    }
    if (t < NC) {
        int i = t << 4;
        int e = i ? sh[i - 1] : 0;
        co[t] = e; ccur[t] = e;
    } else if (t == NC) {
        co[NC] = total;
    }
}

// ---------------- pass 3: coarse partition ----------------
__global__ __launch_bounds__(256)
void part1(const int* __restrict__ dst, const int* __restrict__ src,
           int* __restrict__ ccur, int* __restrict__ cdst, int* __restrict__ csrc, int E) {
    __shared__ int ld[PT1], ls[PT1];
    __shared__ unsigned char lb[PT1];
    __shared__ int hist[NC], lbase[NC], gbase[NC];
    long long t0 = (long long)blockIdx.x * PT1;
    int n = (int)min((long long)PT1, (long long)E - t0);
    int tid = threadIdx.x;
    for (int i = tid; i < NC; i += 256) hist[i] = 0;
    __syncthreads();
    int d[PT1 / 256], s[PT1 / 256], c[PT1 / 256];
#pragma unroll
    for (int k = 0; k < PT1 / 256; ++k) {
        int li = k * 256 + tid;
        if (li < n) {
            d[k] = __builtin_nontemporal_load(dst + t0 + li);
            s[k] = __builtin_nontemporal_load(src + t0 + li);
            c[k] = d[k] >> 11;
            atomicAdd(&hist[c[k]], 1);
        }
    }
    __syncthreads();
    if (tid == 0) {
        int run = 0;
        for (int i = 0; i < NC; ++i) { lbase[i] = run; run += hist[i]; }
    }
    __syncthreads();
    if (tid < NC) gbase[tid] = atomicAdd(&ccur[tid], hist[tid]);
    __syncthreads();
    for (int i = tid; i < NC; i += 256) hist[i] = 0;
    __syncthreads();
#pragma unroll
    for (int k = 0; k < PT1 / 256; ++k) {
        int li = k * 256 + tid;
        if (li < n) {
            int pos = lbase[c[k]] + atomicAdd(&hist[c[k]], 1);
            ld[pos] = d[k]; ls[pos] = s[k]; lb[pos] = (unsigned char)c[k];
        }
    }
    __syncthreads();
    for (int i = tid; i < n; i += 256) {
        int bb = lb[i];
        int g = gbase[bb] + (i - lbase[bb]);
        cdst[g] = ld[i];
        csrc[g] = ls[i];
    }
}

// ---------------- pass 4: fine partition ----------------
__global__ __launch_bounds__(256)
void part2(const int* __restrict__ cdst, const int* __restrict__ csrc,
           const int* __restrict__ co, int* __restrict__ fcur,
           int* __restrict__ qdst, int* __restrict__ qsrc) {
    __shared__ int ld[PT2], ls[PT2];
    __shared__ unsigned char lb[PT2];
    __shared__ int hist[16], lbase[16], gbase[16];
    int c = blockIdx.x / BPC;
    int j = blockIdx.x % BPC;
    int beg = co[c], end = co[c + 1];
    int tid = threadIdx.x;
    for (int t0 = beg + j * PT2; t0 < end; t0 += BPC * PT2) {
        int n = min(PT2, end - t0);
        if (tid < 16) hist[tid] = 0;
        __syncthreads();
        int d[PT2 / 256], s[PT2 / 256], f[PT2 / 256];
#pragma unroll
        for (int k = 0; k < PT2 / 256; ++k) {
            int li = k * 256 + tid;
            if (li < n) {
                d[k] = cdst[t0 + li];
                s[k] = csrc[t0 + li];
                f[k] = (d[k] >> 7) & 15;
                atomicAdd(&hist[f[k]], 1);
            }
        }
        __syncthreads();
        if (tid == 0) {
            int run = 0;
            for (int i = 0; i < 16; ++i) { lbase[i] = run; run += hist[i]; }
        }
        __syncthreads();
        if (tid < 16) gbase[tid] = atomicAdd(&fcur[(c << 4) + tid], hist[tid]);
        __syncthreads();
        if (tid < 16) hist[tid] = 0;
        __syncthreads();
#pragma unroll
        for (int k = 0; k < PT2 / 256; ++k) {
            int li = k * 256 + tid;
            if (li < n) {
                int pos = lbase[f[k]] + atomicAdd(&hist[f[k]], 1);
                ld[pos] = d[k]; ls[pos] = s[k]; lb[pos] = (unsigned char)f[k];
            }
        }
        __syncthreads();
        for (int i = tid; i < n; i += 256) {
            int bb = lb[i];
            int g = gbase[bb] + (i - lbase[bb]);
            qdst[g] = ld[i];
            qsrc[g] = ls[i];
        }
        __syncthreads();
    }
}

// ---------------- pass 5: per-bucket CSR finalize ----------------
__global__ __launch_bounds__(256)
void fill_final(const int* __restrict__ qdst, const int* __restrict__ qsrc,
                const int* __restrict__ bo, int* __restrict__ offs,
                int* __restrict__ nbr, int N, int E) {
    __shared__ int cnt[128], cbase[128], cur[128];
    __shared__ int lout[CAP];
    int b = blockIdx.x;
    int nlo = b << 7;
    int nn = min(128, N - nlo);
    int ebeg = bo[b], ne = bo[b + 1] - ebeg;
    int tid = threadIdx.x;
    if (tid < 128) { cnt[tid] = 0; cur[tid] = 0; }
    __syncthreads();
    for (int i = tid; i < ne; i += 256)
        atomicAdd(&cnt[qdst[ebeg + i] - nlo], 1);
    __syncthreads();
    if (tid < 128) cbase[tid] = cnt[tid];
    __syncthreads();
    for (int st = 1; st < 128; st <<= 1) {
        int v = 0;
        if (tid < 128 && tid >= st) v = cbase[tid - st];
        __syncthreads();
        if (tid < 128 && tid >= st) cbase[tid] += v;
        __syncthreads();
    }
    if (tid < nn)
        offs[nlo + tid] = ebeg + (tid ? cbase[tid - 1] : 0);
    if (b == NB - 1 && tid == 0) offs[N] = E;
    __syncthreads();
    for (int i = tid; i < ne; i += 256) {
        int d = qdst[ebeg + i];
        int s = qsrc[ebeg + i];
        int ln = d - nlo;
        int p = (ln ? cbase[ln - 1] : 0) + atomicAdd(&cur[ln], 1);
        lout[p] = s;
    }
    __syncthreads();
    for (int i = tid; i < ne; i += 256)
        nbr[ebeg + i] = lout[i];
}

// ---------------- layer 1 fused: agg + linear + BN stats; fp16 h1 out ----------------
__global__ __launch_bounds__(256)
void layer1_fused(const float2* __restrict__ x2,
                  const int* __restrict__ offs, const int* __restrict__ nbr,
                  const float* __restrict__ Wl, const float* __restrict__ bl,
                  const float* __restrict__ Wr,
                  __half* __restrict__ hout16,
                  double* __restrict__ sums, int N) {
    __shared__ float sAr[64];
    int tid = threadIdx.x;
    if (tid < 64) sAr[tid] = 0.f;
    __syncthreads();
    int n = blockIdx.x * 256 + tid;
    bool valid = (n < N);
    int beg = 0, end = 0;
    if (valid) { beg = offs[n]; end = offs[n + 1]; }
    float ax0 = 0.f, ay0 = 0.f, ax1 = 0.f, ay1 = 0.f;
    int j = beg;
    // 16-deep gather: 16 independent loads in flight (x table is L2-resident)
    for (; j + 16 <= end; j += 16) {
        int s[16];
#pragma unroll
        for (int u = 0; u < 16; ++u) s[u] = __builtin_nontemporal_load(nbr + j + u);
        float2 v[16];
#pragma unroll
        for (int u = 0; u < 16; ++u) v[u] = x2[s[u]];
#pragma unroll
        for (int u = 0; u < 16; ++u) {
            if (u & 1) { ax1 += v[u].x; ay1 += v[u].y; }
            else       { ax0 += v[u].x; ay0 += v[u].y; }
        }
    }
    for (; j + 4 <= end; j += 4) {
        int s[4];
#pragma unroll
        for (int u = 0; u < 4; ++u) s[u] = __builtin_nontemporal_load(nbr + j + u);
        float2 v[4];
#pragma unroll
        for (int u = 0; u < 4; ++u) v[u] = x2[s[u]];
        ax0 += v[0].x; ay0 += v[0].y;
        ax1 += v[1].x; ay1 += v[1].y;
        ax0 += v[2].x; ay0 += v[2].y;
        ax1 += v[3].x; ay1 += v[3].y;
    }
    for (; j < end; ++j) {
        float2 v = x2[nbr[j]];
        ax0 += v.x; ay0 += v.y;
    }
    float invd = 1.0f / fmaxf((float)(end - beg), 1.0f);
    float a0 = (ax0 + ax1) * invd, a1 = (ay0 + ay1) * invd;
    float x0 = 0.f, x1 = 0.f;
    if (valid) {
        float2 xv = x2[n];
        x0 = xv.x; x1 = xv.y;
    }
    float acc[32];
#pragma unroll
    for (int jj = 0; jj < 32; ++jj)
        acc[jj] = bl[jj] + a0 * Wl[jj] + a1 * Wl[32 + jj] + x0 * Wr[jj] + x1 * Wr[32 + jj];
    if (valid) {
        unsigned w[16];
#pragma unroll
        for (int p = 0; p < 16; ++p) w[p] = pack_h2(acc[2*p], acc[2*p+1]);
        uint4* q = (uint4*)(hout16 + (size_t)n * 32);
        q[0] = make_uint4(w[0], w[1], w[2], w[3]);
        q[1] = make_uint4(w[4], w[5], w[6], w[7]);
        q[2] = make_uint4(w[8], w[9], w[10], w[11]);
        q[3] = make_uint4(w[12], w[13], w[14], w[15]);
    }
    int lane = tid & 63;
#pragma unroll
    for (int jj = 0; jj < 32; ++jj) {
        float v = valid ? acc[jj] : 0.f;
        float s = bfly64(v);
        float q = bfly64(v * v);
        if (lane == jj) atomicAdd(&sAr[jj], s);
        if (lane == 32 + jj) atomicAdd(&sAr[32 + jj], q);
    }
    __syncthreads();
    if (tid < 64) atomicAdd(&sums[tid], (double)sAr[tid]);
}

// ---------------- per-node BN+ReLU apply: h -> b (fp16), once per node ----------------
template<int F>
__global__ __launch_bounds__(256)
void bn_apply(const uint4* __restrict__ h, const double* __restrict__ sums,
              const float* __restrict__ gamma, const float* __restrict__ beta,
              uint4* __restrict__ out, int N) {
    __shared__ __align__(16) float lsc[F], lsf[F];
    int tid = threadIdx.x;
    if (tid < F) {
        double mu = sums[tid] / (double)N_NODES;
        double var = sums[F + tid] / (double)N_NODES - mu * mu;
        if (var < 0.0) var = 0.0;
        double sc = (double)gamma[tid] / sqrt(var + BN_EPS);
        lsc[tid] = (float)sc;
        lsf[tid] = (float)((double)beta[tid] - mu * sc);
    }
    __syncthreads();
    constexpr int FV = F / 8;
    int total = N * FV;
    for (int i = blockIdx.x * 256 + tid; i < total; i += gridDim.x * 256) {
        uint4 v = h[i];
        int c4 = (i & (FV - 1)) * 2;      // float4 index of first quad
        float4 sca = ((const float4*)lsc)[c4];
        float4 scb = ((const float4*)lsc)[c4 + 1];
        float4 sfa = ((const float4*)lsf)[c4];
        float4 sfb = ((const float4*)lsf)[c4 + 1];
        float2 f0 = unpack_h2(v.x), f1 = unpack_h2(v.y);
        float2 f2 = unpack_h2(v.z), f3 = unpack_h2(v.w);
        uint4 o;
        o.x = pack_h2(fmaxf(f0.x * sca.x + sfa.x, 0.f), fmaxf(f0.y * sca.y + sfa.y, 0.f));
        o.y = pack_h2(fmaxf(f1.x * sca.z + sfa.z, 0.f), fmaxf(f1.y * sca.w + sfa.w, 0.f));
        o.z = pack_h2(fmaxf(f2.x * scb.x + sfb.x, 0.f), fmaxf(f2.y * scb.y + sfb.y, 0.f));
        o.w = pack_h2(fmaxf(f3.x * scb.z + sfb.z, 0.f), fmaxf(f3.y * scb.w + sfb.w, 0.f));
        out[i] = o;
    }
}

// ---------------- fp16 sum-gather agg, 16-deep MLP, fp32 dual-bank accum ----------------
__device__ __forceinline__ void accum8_h16(float* acc, uint4 v) {
    float2 f0 = unpack_h2(v.x), f1 = unpack_h2(v.y);
    float2 f2 = unpack_h2(v.z), f3 = unpack_h2(v.w);
    acc[0] += f0.x; acc[1] += f0.y; acc[2] += f1.x; acc[3] += f1.y;
    acc[4] += f2.x; acc[5] += f2.y; acc[6] += f3.x; acc[7] += f3.y;
}

template<int F>
__global__ __launch_bounds__(256)
void agg_sum(const uint4* __restrict__ xb, const int* __restrict__ offs,
             const int* __restrict__ nbr, uint4* __restrict__ aggh, int N) {
    constexpr int FV = F / 8;            // uint4 lanes per row
    constexpr int NPB = 256 / FV;        // nodes per block
    int n = blockIdx.x * NPB + threadIdx.y;
    if (n >= N) return;
    int f = threadIdx.x;
    int beg = offs[n], end = offs[n + 1];
    float a0[8], a1[8];
#pragma unroll
    for (int q = 0; q < 8; ++q) { a0[q] = 0.f; a1[q] = 0.f; }
    int j = beg;
    // 16-deep main loop: 16 independent gathers in flight per thread
    for (; j + 16 <= end; j += 16) {
        int s[16];
#pragma unroll
        for (int u = 0; u < 16; ++u) s[u] = __builtin_nontemporal_load(nbr + j + u);
        uint4 v[16];
#pragma unroll
        for (int u = 0; u < 16; ++u) v[u] = xb[s[u] * FV + f];
#pragma unroll
        for (int u = 0; u < 16; ++u)
            accum8_h16((u & 1) ? a1 : a0, v[u]);
    }
    if (j + 8 <= end) {
        int s[8];
#pragma unroll
        for (int u = 0; u < 8; ++u) s[u] = __builtin_nontemporal_load(nbr + j + u);
        uint4 v[8];
#pragma unroll
        for (int u = 0; u < 8; ++u) v[u] = xb[s[u] * FV + f];
#pragma unroll
        for (int u = 0; u < 8; ++u)
            accum8_h16((u & 1) ? a1 : a0, v[u]);
        j += 8;
    }
    if (j + 4 <= end) {
        int s[4];
#pragma unroll
        for (int u = 0; u < 4; ++u) s[u] = __builtin_nontemporal_load(nbr + j + u);
        uint4 v[4];
#pragma unroll
        for (int u = 0; u < 4; ++u) v[u] = xb[s[u] * FV + f];
#pragma unroll
        for (int u = 0; u < 4; ++u)
            accum8_h16((u & 1) ? a1 : a0, v[u]);
        j += 4;
    }
    for (; j < end; ++j) {
        uint4 v = xb[__builtin_nontemporal_load(nbr + j) * FV + f];
        accum8_h16(a0, v);
    }
    float invd = 1.0f / fmaxf((float)(end - beg), 1.0f);
    uint4 o;
    o.x = pack_h2((a0[0] + a1[0]) * invd, (a0[1] + a1[1]) * invd);
    o.y = pack_h2((a0[2] + a1[2]) * invd, (a0[3] + a1[3]) * invd);
    o.z = pack_h2((a0[4] + a1[4]) * invd, (a0[5] + a1[5]) * invd);
    o.w = pack_h2((a0[6] + a1[6]) * invd, (a0[7] + a1[7]) * invd);
    aggh[n * FV + f] = o;
}

// ---------------- weight packing for MFMA: W -> (hi, lo) fp16 fragment order ----------------
// frag[kb][cb][lane][i] holds W[kb*32 + (lane>>4)*8 + i][cb*16 + (lane&15)].
// A-load and B-pack use the SAME (lane,i)->k map; only C/D layout matters (HW-verified).
__global__ __launch_bounds__(256)
void pack_w(const float* __restrict__ Wl2, const float* __restrict__ Wr2,
            const float* __restrict__ Wl3, const float* __restrict__ Wr3,
            __half* __restrict__ pk) {
    int e = blockIdx.x * 256 + threadIdx.x;   // grid is exactly 80*256 = 20480
    const float* W; int le, DOUT, NCB, base, SZ;
    if (e < 2048)       { W = Wl2; le = e;         DOUT = 64;  NCB = 4; base = 0;     SZ = 2048; }
    else if (e < 4096)  { W = Wr2; le = e - 2048;  DOUT = 64;  NCB = 4; base = 4096;  SZ = 2048; }
    else if (e < 12288) { W = Wl3; le = e - 4096;  DOUT = 128; NCB = 8; base = 8192;  SZ = 8192; }
    else                { W = Wr3; le = e - 12288; DOUT = 128; NCB = 8; base = 24576; SZ = 8192; }
    int i = le & 7;
    int lane = (le >> 3) & 63;
    int cbkb = le >> 9;
    int cb = cbkb % NCB;
    int kb = cbkb / NCB;
    int k = kb * 32 + ((lane >> 4) << 3) + i;
    int col = cb * 16 + (lane & 15);
    float w = W[k * DOUT + col];
    __half h = __float2half(w);
    float lo = w - __half2float(h);
    pk[base + le] = h;
    pk[base + SZ + le] = __float2half(lo);
}

// ---------------- MFMA linear: pure-load fp16 fragments (agg pre-scaled, x pre-BN'd),
// split-fp16 weights, fp32 MFMA accumulate, fp16 out, fused BN-stats partials ----------------
template<int DIN, int DOUT>
__global__ __launch_bounds__(256)
void linear_mfma(const __half* __restrict__ bnx16, const __half* __restrict__ agg16,
                 const __half* __restrict__ wlhi, const __half* __restrict__ wllo,
                 const __half* __restrict__ wrhi, const __half* __restrict__ wrlo,
                 const float* __restrict__ bl,
                 __half* __restrict__ hout16, float* __restrict__ partial, int N) {
    constexpr int KB = DIN / 32;    // K-slabs of 32
    constexpr int NCB = DOUT / 16;  // col-blocks of 16
    constexpr int MREP = 2;         // 16-row fragments per wave
    constexpr int MB = 4 * MREP * 16;  // 128 rows per block
    __shared__ float blkS[DOUT], blkQ[DOUT];
    int tid = threadIdx.x;
    for (int i = tid; i < DOUT; i += 256) { blkS[i] = 0.f; blkQ[i] = 0.f; }
    __syncthreads();
    int n0 = blockIdx.x * MB;

    int wave = tid >> 6;
    int lane = tid & 63;
    int rlane = lane & 15;
    int kg = lane >> 4;          // 0..3 -> k-group of 8
    int rbase = n0 + wave * (MREP * 16);

    // ---- A fragments: pure vector loads ----
    f16x8 aA[MREP][KB], aX[MREP][KB];
#pragma unroll
    for (int m = 0; m < MREP; ++m) {
        int row = rbase + m * 16 + rlane;
        int rowc = min(row, N - 1);
#pragma unroll
        for (int kb = 0; kb < KB; ++kb) {
            int c0 = kb * 32 + kg * 8;
            F16x8u ta, tx;
            ta.u = *(const uint4*)(agg16 + (size_t)rowc * DIN + c0);
            tx.u = *(const uint4*)(bnx16 + (size_t)rowc * DIN + c0);
            aA[m][kb] = ta.v;
            aX[m][kb] = tx.v;
        }
    }

    // ---- accumulators init with bias (D layout: row=(lane>>4)*4+r, col=lane&15) ----
    f32x4 acc[MREP][NCB];
#pragma unroll
    for (int cb = 0; cb < NCB; ++cb) {
        float bv = bl[cb * 16 + rlane];
#pragma unroll
        for (int m = 0; m < MREP; ++m)
            acc[m][cb] = {bv, bv, bv, bv};
    }

    // ---- MFMA main: acc += aA*(Wl_hi+Wl_lo) + aX*(Wr_hi+Wr_lo) ----
#pragma unroll
    for (int cb = 0; cb < NCB; ++cb) {
#pragma unroll
        for (int kb = 0; kb < KB; ++kb) {
            size_t fo = ((size_t)(kb * NCB + cb) * 64 + lane) * 8;
            f16x8 blh = *(const f16x8*)(wlhi + fo);
            f16x8 bll = *(const f16x8*)(wllo + fo);
            f16x8 brh = *(const f16x8*)(wrhi + fo);
            f16x8 brl = *(const f16x8*)(wrlo + fo);
#pragma unroll
            for (int m = 0; m < MREP; ++m) {
                acc[m][cb] = __builtin_amdgcn_mfma_f32_16x16x32_f16(aA[m][kb], blh, acc[m][cb], 0, 0, 0);
                acc[m][cb] = __builtin_amdgcn_mfma_f32_16x16x32_f16(aA[m][kb], bll, acc[m][cb], 0, 0, 0);
                acc[m][cb] = __builtin_amdgcn_mfma_f32_16x16x32_f16(aX[m][kb], brh, acc[m][cb], 0, 0, 0);
                acc[m][cb] = __builtin_amdgcn_mfma_f32_16x16x32_f16(aX[m][kb], brl, acc[m][cb], 0, 0, 0);
            }
        }
    }

    // ---- store fp16 outputs ----
#pragma unroll
    for (int m = 0; m < MREP; ++m) {
        int rowb = rbase + m * 16 + kg * 4;
#pragma unroll
        for (int r = 0; r < 4; ++r) {
            int node = rowb + r;
            if (node < N) {
#pragma unroll
                for (int cb = 0; cb < NCB; ++cb)
                    hout16[(size_t)node * DOUT + cb * 16 + rlane] = __float2half(acc[m][cb][r]);
            }
        }
    }

    // ---- fused BN-stats partials: per-block sum/sumsq per feature ----
#pragma unroll
    for (int cb = 0; cb < NCB; ++cb) {
        float s = 0.f, q = 0.f;
#pragma unroll
        for (int m = 0; m < MREP; ++m) {
            int rowb = rbase + m * 16 + kg * 4;
#pragma unroll
            for (int r = 0; r < 4; ++r) {
                if (rowb + r < N) {
                    float v = acc[m][cb][r];
                    s += v; q += v * v;
                }
            }
        }
        s += __shfl_xor(s, 16, 64); s += __shfl_xor(s, 32, 64);
        q += __shfl_xor(q, 16, 64); q += __shfl_xor(q, 32, 64);
        if (kg == 0) {
            atomicAdd(&blkS[cb * 16 + rlane], s);
            atomicAdd(&blkQ[cb * 16 + rlane], q);
        }
    }
    __syncthreads();
    float* po = partial + (size_t)blockIdx.x * (2 * DOUT);
    for (int i = tid; i < DOUT; i += 256) {
        po[i] = blkS[i];
        po[DOUT + i] = blkQ[i];
    }
}

// ---------------- stats finalize: reduce P block-partials per feature in fp64, fixed order ----------------
template<int F>
__global__ __launch_bounds__(256)
void stats_finalize2(const float* __restrict__ partial, double* __restrict__ sums, int P) {
    __shared__ double sh[256];
    int i = blockIdx.x;
    int t = threadIdx.x;
    double a = 0.0;
    for (int k = t; k < P; k += 256)
        a += (double)partial[(size_t)k * (2 * F) + i];
    sh[t] = a;
    __syncthreads();
    for (int st = 128; st > 0; st >>= 1) {
        if (t < st) sh[t] += sh[t + st];
        __syncthreads();
    }
    if (t == 0) sums[i] = sh[0];
}

// ---------------- pool (fp16 h3) with inline BN3 finalize + fused ReLU ----------------
__global__ void pool_partial(const __half* __restrict__ h, const int* __restrict__ batch,
                             const double* __restrict__ sums,
                             const float* __restrict__ gamma, const float* __restrict__ beta,
                             double* __restrict__ pooled_d, int N) {
    __shared__ float lsc[128], lsf[128];
    const int CH = 64;
    int f = threadIdx.x;
    {
        double mu = sums[f] / (double)N_NODES;
        double var = sums[128 + f] / (double)N_NODES - mu * mu;
        if (var < 0.0) var = 0.0;
        double sc = (double)gamma[f] / sqrt(var + BN_EPS);
        lsc[f] = (float)sc;
        lsf[f] = (float)((double)beta[f] - mu * sc);
    }
    __syncthreads();
    int n0 = blockIdx.x * CH;
    if (n0 >= N) return;
    int n1 = min(n0 + CH, N);
    float sc = lsc[f], sf = lsf[f];
    int g = batch[n0];
    float acc = 0.f;
    for (int n = n0; n < n1; ++n) {
        int bg = batch[n];
        if (bg != g) {
            atomicAdd(&pooled_d[g * 128 + f], (double)acc);
            acc = 0.f;
            g = bg;
        }
        float v = __half2float(h[(long long)n * 128 + f]);
        acc += fmaxf(v * sc + sf, 0.f);
    }
    atomicAdd(&pooled_d[g * 128 + f], (double)acc);
}

// ---------------- fused pool-finalize + head MLP ----------------
__global__ void mlp_fused(const double* __restrict__ pooled_d, const int* __restrict__ batch,
                          const float* __restrict__ Wf1, const float* __restrict__ bf1,
                          const float* __restrict__ Wf2, const float* __restrict__ bf2,
                          float* __restrict__ out, int N) {
    __shared__ float sp[128];
    int g = blockIdx.x;
    int t = threadIdx.x;
    int lo = 0, hi = N;
    while (lo < hi) { int m = (lo + hi) >> 1; if (batch[m] < g) lo = m + 1; else hi = m; }
    int start = lo;
    hi = N;
    while (lo < hi) { int m = (lo + hi) >> 1; if (batch[m] < g + 1) lo = m + 1; else hi = m; }
    int cnt = lo - start;
    sp[t] = (float)(pooled_d[g * 128 + t] / (double)max(cnt, 1));
    __syncthreads();
    if (t < 64) {
        float hacc = bf1[t];
#pragma unroll 8
        for (int k = 0; k < 128; ++k) hacc += sp[k] * Wf1[k * 64 + t];
        hacc = fmaxf(hacc, 0.f) * Wf2[t];
        for (int o = 32; o > 0; o >>= 1) hacc += __shfl_down(hacc, o);
        if (t == 0) out[g] = hacc + bf2[0];
    }
}

extern "C" void kernel_launch(void* const* d_in, const int* in_sizes, int n_in,
                              void* d_out, int out_size, void* d_ws, size_t ws_size,
                              hipStream_t stream) {
    const float* x     = (const float*)d_in[0];
    const int*   ei    = (const int*)d_in[1];
    const int*   batch = (const int*)d_in[2];
    const float *Wl1=(const float*)d_in[3],  *bl1=(const float*)d_in[4],  *Wr1=(const float*)d_in[5];
    const float *g1 =(const float*)d_in[6],  *be1=(const float*)d_in[7];
    const float *Wl2=(const float*)d_in[8],  *bl2=(const float*)d_in[9],  *Wr2=(const float*)d_in[10];
    const float *g2 =(const float*)d_in[11], *be2=(const float*)d_in[12];
    const float *Wl3=(const float*)d_in[13], *bl3=(const float*)d_in[14], *Wr3=(const float*)d_in[15];
    const float *g3 =(const float*)d_in[16], *be3=(const float*)d_in[17];
    const float *Wf1=(const float*)d_in[18], *bf1=(const float*)d_in[19];
    const float *Wf2=(const float*)d_in[20], *bf2=(const float*)d_in[21];

    const int N = N_NODES;
    const int E = in_sizes[1] / 2;
    const int* src = ei;
    const int* dst = ei + E;

    char* ws = (char*)d_ws;
    size_t off = 0;
    auto salloc = [&](size_t bytes) {
        void* p = ws + off;
        off += (bytes + 255) & ~(size_t)255;
        return p;
    };
    // --- zero-init region (one memset) ---
    int*    bhist   = (int*)   salloc(NB * 4);
    double* sums    = (double*)salloc(768 * 8);
    double* pooledd = (double*)salloc((size_t)N_GRAPHS * 128 * 8);
    size_t zero_bytes = off;
    // --- rest ---
    int*    offs    = (int*)   salloc((size_t)(N + 1) * 4);
    int*    bo      = (int*)   salloc((NB + 1) * 4);
    int*    fcur    = (int*)   salloc(784 * 4);
    int*    co      = (int*)   salloc((NC + 1) * 4);
    int*    ccur    = (int*)   salloc(NC * 4);
    int*    nbr     = (int*)   salloc((size_t)E * 4);
    float*  partial = (float*) salloc((size_t)1024 * 256 * 4);       // 1 MB (stats partials)
    __half* pk      = (__half*)salloc((size_t)40960 * 2);            // 80 KB packed weights
    __half* h1h     = (__half*)salloc((size_t)(N + 256) * 32 * 2);   // 6.4 MB
    __half* b1h     = (__half*)salloc((size_t)(N + 256) * 32 * 2);   // 6.4 MB bnrelu(h1)
    __half* h2h     = (__half*)salloc((size_t)(N + 256) * 64 * 2);   // 12.8 MB
    __half* b2h     = (__half*)salloc((size_t)(N + 256) * 64 * 2);   // 12.8 MB bnrelu(h2)
    __half* h3h     = (__half*)salloc((size_t)(N + 256) * 128 * 2);  // 25.7 MB (hosts cdst/csrc early)
    __half* aggh    = (__half*)salloc((size_t)(N + 256) * 64 * 2);   // 12.8 MB (hosts qdst/qsrc early)
    (void)ws_size;

    double* sums1 = sums, *sums2 = sums + 256, *sums3 = sums + 512;
    int* cdst = (int*)h3h;
    int* csrc = cdst + E;
    int* qdst = (int*)aggh;
    int* qsrc = qdst + E;

    const __half *pwl2h = pk,         *pwl2l = pk + 2048;
    const __half *pwr2h = pk + 4096,  *pwr2l = pk + 6144;
    const __half *pwl3h = pk + 8192,  *pwl3l = pk + 16384;
    const __half *pwr3h = pk + 24576, *pwr3l = pk + 32768;

    hipMemsetAsync(bhist, 0, zero_bytes, stream);

    // ---- weight packing (tiny; independent of CSR build) ----
    pack_w<<<80, 256, 0, stream>>>(Wl2, Wr2, Wl3, Wr3, pk);

    // ---- CSR build ----
    hist_fine<<<1024, 256, 0, stream>>>(dst, bhist, E);
    scan_buckets<<<1, 1024, 0, stream>>>(bhist, bo, fcur, co, ccur);
    part1<<<(E + PT1 - 1) / PT1, 256, 0, stream>>>(dst, src, ccur, cdst, csrc, E);
    part2<<<NC * BPC, 256, 0, stream>>>(cdst, csrc, co, fcur, qdst, qsrc);
    fill_final<<<NB, 256, 0, stream>>>(qdst, qsrc, bo, offs, nbr, N, E);

    const int NL = (N + 255) / 256;
    const int NBLK = (N + 127) / 128;   // 782 blocks for linear_mfma

    // ---- layer 1: fused agg + linear + stats -> fp16 h1 ----
    layer1_fused<<<NL, 256, 0, stream>>>((const float2*)x, offs, nbr,
                                          Wl1, bl1, Wr1, h1h, sums1, N);

    // ---- layer 2 ----
    bn_apply<32><<<512, 256, 0, stream>>>((const uint4*)h1h, sums1, g1, be1, (uint4*)b1h, N);
    agg_sum<32><<<(N + 63) / 64, dim3(4, 64), 0, stream>>>(
        (const uint4*)b1h, offs, nbr, (uint4*)aggh, N);
    linear_mfma<32, 64><<<NBLK, 256, 0, stream>>>(
        b1h, (const __half*)aggh, pwl2h, pwl2l, pwr2h, pwr2l, bl2, h2h, partial, N);
    stats_finalize2<64><<<128, 256, 0, stream>>>(partial, sums2, NBLK);

    // ---- layer 3 ----
    bn_apply<64><<<512, 256, 0, stream>>>((const uint4*)h2h, sums2, g2, be2, (uint4*)b2h, N);
    agg_sum<64><<<(N + 31) / 32, dim3(8, 32), 0, stream>>>(
        (const uint4*)b2h, offs, nbr, (uint4*)aggh, N);
    linear_mfma<64, 128><<<NBLK, 256, 0, stream>>>(
        b2h, (const __half*)aggh, pwl3h, pwl3l, pwr3h, pwr3l, bl3, h3h, partial, N);
    stats_finalize2<128><<<256, 256, 0, stream>>>(partial, sums3, NBLK);

    // ---- pool + head ----
    pool_partial<<<(N + 63) / 64, 128, 0, stream>>>(h3h, batch, sums3, g3, be3, pooledd, N);
    mlp_fused<<<N_GRAPHS, 128, 0, stream>>>(pooledd, batch, Wf1, bf1, Wf2, bf2, (float*)d_out, N);
}

// Round 11
// 312.415 us; speedup vs baseline: 1.4206x; 1.0831x over previous
//
#include <hip/hip_runtime.h>
#include <hip/hip_fp16.h>

#define N_NODES 100000
#define N_GRAPHS 64
#define BN_EPS 1e-5

#define NB 782
#define NC 49
#define PT1 4096
#define PT2 2048
#define BPC 16
#define CAP 3072
#define CAPC 36864   // fixed coarse-bucket capacity (mean 32768, sigma~181 -> 22 sigma margin)
#define CAPF 3072    // fixed fine-bucket capacity (mean 2046; lout[CAP] already assumes <=3072)

typedef _Float16 f16x8 __attribute__((ext_vector_type(8)));
typedef float f32x4 __attribute__((ext_vector_type(4)));

union F16x8u {
    f16x8 v;
    __half2 h2[4];
    uint4 u;
};

__device__ __forceinline__ float bfly64(float v) {
#pragma unroll
    for (int m = 1; m < 64; m <<= 1) v += __shfl_xor(v, m, 64);
    return v;
}

__device__ __forceinline__ unsigned pack_h2(float a, float b) {
    __half2 h = __floats2half2_rn(a, b);
    unsigned w;
    __builtin_memcpy(&w, &h, 4);
    return w;
}

__device__ __forceinline__ float2 unpack_h2(unsigned w) {
    __half2 h;
    __builtin_memcpy(&h, &w, 4);
    return __half22float2(h);
}

// ---------------- cursor init: fixed-capacity bucket bases ----------------
__global__ void cur_init(int* __restrict__ ccur, int* __restrict__ fcur) {
    int t = threadIdx.x;
    if (t < NC) ccur[t] = t * CAPC;
    if (t < 784) fcur[t] = t * CAPF;
}

// ---------------- pass 1: coarse partition (atomic region cursors, no pre-scan) ----------------
__global__ __launch_bounds__(256)
void part1(const int* __restrict__ dst, const int* __restrict__ src,
           int* __restrict__ ccur, int* __restrict__ cdst, int* __restrict__ csrc, int E) {
    __shared__ int ld[PT1], ls[PT1];
    __shared__ unsigned char lb[PT1];
    __shared__ int hist[NC], lbase[NC], gbase[NC];
    long long t0 = (long long)blockIdx.x * PT1;
    int n = (int)min((long long)PT1, (long long)E - t0);
    int tid = threadIdx.x;
    for (int i = tid; i < NC; i += 256) hist[i] = 0;
    __syncthreads();
    int d[PT1 / 256], s[PT1 / 256], c[PT1 / 256];
#pragma unroll
    for (int k = 0; k < PT1 / 256; ++k) {
        int li = k * 256 + tid;
        if (li < n) {
            d[k] = __builtin_nontemporal_load(dst + t0 + li);
            s[k] = __builtin_nontemporal_load(src + t0 + li);
            c[k] = d[k] >> 11;
            atomicAdd(&hist[c[k]], 1);
        }
    }
    __syncthreads();
    if (tid == 0) {
        int run = 0;
        for (int i = 0; i < NC; ++i) { lbase[i] = run; run += hist[i]; }
    }
    __syncthreads();
    if (tid < NC) gbase[tid] = atomicAdd(&ccur[tid], hist[tid]);
    __syncthreads();
    for (int i = tid; i < NC; i += 256) hist[i] = 0;
    __syncthreads();
#pragma unroll
    for (int k = 0; k < PT1 / 256; ++k) {
        int li = k * 256 + tid;
        if (li < n) {
            int pos = lbase[c[k]] + atomicAdd(&hist[c[k]], 1);
            ld[pos] = d[k]; ls[pos] = s[k]; lb[pos] = (unsigned char)c[k];
        }
    }
    __syncthreads();
    for (int i = tid; i < n; i += 256) {
        int bb = lb[i];
        int g = gbase[bb] + (i - lbase[bb]);
        cdst[g] = ld[i];
        csrc[g] = ls[i];
    }
}

// ---------------- pass 2: fine partition (reads final coarse cursors for counts) ----------------
__global__ __launch_bounds__(256)
void part2(const int* __restrict__ cdst, const int* __restrict__ csrc,
           const int* __restrict__ ccur, int* __restrict__ fcur,
           int* __restrict__ qdst, int* __restrict__ qsrc) {
    __shared__ int ld[PT2], ls[PT2];
    __shared__ unsigned char lb[PT2];
    __shared__ int hist[16], lbase[16], gbase[16];
    int c = blockIdx.x / BPC;
    int j = blockIdx.x % BPC;
    int beg = c * CAPC;
    int end = ccur[c];          // final cursor = base + count
    int tid = threadIdx.x;
    for (int t0 = beg + j * PT2; t0 < end; t0 += BPC * PT2) {
        int n = min(PT2, end - t0);
        if (tid < 16) hist[tid] = 0;
        __syncthreads();
        int d[PT2 / 256], s[PT2 / 256], f[PT2 / 256];
#pragma unroll
        for (int k = 0; k < PT2 / 256; ++k) {
            int li = k * 256 + tid;
            if (li < n) {
                d[k] = cdst[t0 + li];
                s[k] = csrc[t0 + li];
                f[k] = (d[k] >> 7) & 15;
                atomicAdd(&hist[f[k]], 1);
            }
        }
        __syncthreads();
        if (tid == 0) {
            int run = 0;
            for (int i = 0; i < 16; ++i) { lbase[i] = run; run += hist[i]; }
        }
        __syncthreads();
        if (tid < 16) gbase[tid] = atomicAdd(&fcur[(c << 4) + tid], hist[tid]);
        __syncthreads();
        if (tid < 16) hist[tid] = 0;
        __syncthreads();
#pragma unroll
        for (int k = 0; k < PT2 / 256; ++k) {
            int li = k * 256 + tid;
            if (li < n) {
                int pos = lbase[f[k]] + atomicAdd(&hist[f[k]], 1);
                ld[pos] = d[k]; ls[pos] = s[k]; lb[pos] = (unsigned char)f[k];
            }
        }
        __syncthreads();
        for (int i = tid; i < n; i += 256) {
            int bb = lb[i];
            int g = gbase[bb] + (i - lbase[bb]);
            qdst[g] = ld[i];
            qsrc[g] = ls[i];
        }
        __syncthreads();
    }
}

// ---------------- pass 3: per-bucket CSR finalize (emits beg + end arrays) ----------------
__global__ __launch_bounds__(256)
void fill_final(const int* __restrict__ qdst, const int* __restrict__ qsrc,
                const int* __restrict__ fcur, int* __restrict__ offs,
                int* __restrict__ oend, int* __restrict__ nbr, int N) {
    __shared__ int cnt[128], cbase[128], cur[128];
    __shared__ int lout[CAP];
    int b = blockIdx.x;
    int nlo = b << 7;
    int nn = min(128, N - nlo);
    int ebeg = b * CAPF;
    int ne = fcur[b] - ebeg;    // final cursor - base = count
    int tid = threadIdx.x;
    if (tid < 128) { cnt[tid] = 0; cur[tid] = 0; }
    __syncthreads();
    for (int i = tid; i < ne; i += 256)
        atomicAdd(&cnt[qdst[ebeg + i] - nlo], 1);
    __syncthreads();
    if (tid < 128) cbase[tid] = cnt[tid];
    __syncthreads();
    for (int st = 1; st < 128; st <<= 1) {
        int v = 0;
        if (tid < 128 && tid >= st) v = cbase[tid - st];
        __syncthreads();
        if (tid < 128 && tid >= st) cbase[tid] += v;
        __syncthreads();
    }
    if (tid < nn) {
        offs[nlo + tid] = ebeg + (tid ? cbase[tid - 1] : 0);
        oend[nlo + tid] = ebeg + cbase[tid];
    }
    __syncthreads();
    for (int i = tid; i < ne; i += 256) {
        int d = qdst[ebeg + i];
        int s = qsrc[ebeg + i];
        int ln = d - nlo;
        int p = (ln ? cbase[ln - 1] : 0) + atomicAdd(&cur[ln], 1);
        lout[p] = s;
    }
    __syncthreads();
    for (int i = tid; i < ne; i += 256)
        nbr[ebeg + i] = lout[i];
}

// ---------------- layer 1 fused: agg + linear + BN stats; fp16 h1 out ----------------
__global__ __launch_bounds__(256)
void layer1_fused(const float2* __restrict__ x2,
                  const int* __restrict__ offs, const int* __restrict__ oend,
                  const int* __restrict__ nbr,
                  const float* __restrict__ Wl, const float* __restrict__ bl,
                  const float* __restrict__ Wr,
                  __half* __restrict__ hout16,
                  double* __restrict__ sums, int N) {
    __shared__ float sAr[64];
    int tid = threadIdx.x;
    if (tid < 64) sAr[tid] = 0.f;
    __syncthreads();
    int n = blockIdx.x * 256 + tid;
    bool valid = (n < N);
    int beg = 0, end = 0;
    if (valid) { beg = offs[n]; end = oend[n]; }
    float ax0 = 0.f, ay0 = 0.f, ax1 = 0.f, ay1 = 0.f;
    int j = beg;
    for (; j + 16 <= end; j += 16) {
        int s[16];
#pragma unroll
        for (int u = 0; u < 16; ++u) s[u] = __builtin_nontemporal_load(nbr + j + u);
        float2 v[16];
#pragma unroll
        for (int u = 0; u < 16; ++u) v[u] = x2[s[u]];
#pragma unroll
        for (int u = 0; u < 16; ++u) {
            if (u & 1) { ax1 += v[u].x; ay1 += v[u].y; }
            else       { ax0 += v[u].x; ay0 += v[u].y; }
        }
    }
    for (; j + 4 <= end; j += 4) {
        int s[4];
#pragma unroll
        for (int u = 0; u < 4; ++u) s[u] = __builtin_nontemporal_load(nbr + j + u);
        float2 v[4];
#pragma unroll
        for (int u = 0; u < 4; ++u) v[u] = x2[s[u]];
        ax0 += v[0].x; ay0 += v[0].y;
        ax1 += v[1].x; ay1 += v[1].y;
        ax0 += v[2].x; ay0 += v[2].y;
        ax1 += v[3].x; ay1 += v[3].y;
    }
    for (; j < end; ++j) {
        float2 v = x2[nbr[j]];
        ax0 += v.x; ay0 += v.y;
    }
    float invd = 1.0f / fmaxf((float)(end - beg), 1.0f);
    float a0 = (ax0 + ax1) * invd, a1 = (ay0 + ay1) * invd;
    float x0 = 0.f, x1 = 0.f;
    if (valid) {
        float2 xv = x2[n];
        x0 = xv.x; x1 = xv.y;
    }
    float acc[32];
#pragma unroll
    for (int jj = 0; jj < 32; ++jj)
        acc[jj] = bl[jj] + a0 * Wl[jj] + a1 * Wl[32 + jj] + x0 * Wr[jj] + x1 * Wr[32 + jj];
    if (valid) {
        unsigned w[16];
#pragma unroll
        for (int p = 0; p < 16; ++p) w[p] = pack_h2(acc[2*p], acc[2*p+1]);
        uint4* q = (uint4*)(hout16 + (size_t)n * 32);
        q[0] = make_uint4(w[0], w[1], w[2], w[3]);
        q[1] = make_uint4(w[4], w[5], w[6], w[7]);
        q[2] = make_uint4(w[8], w[9], w[10], w[11]);
        q[3] = make_uint4(w[12], w[13], w[14], w[15]);
    }
    int lane = tid & 63;
#pragma unroll
    for (int jj = 0; jj < 32; ++jj) {
        float v = valid ? acc[jj] : 0.f;
        float s = bfly64(v);
        float q = bfly64(v * v);
        if (lane == jj) atomicAdd(&sAr[jj], s);
        if (lane == 32 + jj) atomicAdd(&sAr[32 + jj], q);
    }
    __syncthreads();
    if (tid < 64) atomicAdd(&sums[tid], (double)sAr[tid]);
}

// ---------------- per-node BN+ReLU apply: h -> b (fp16), once per node ----------------
template<int F>
__global__ __launch_bounds__(256)
void bn_apply(const uint4* __restrict__ h, const double* __restrict__ sums,
              const float* __restrict__ gamma, const float* __restrict__ beta,
              uint4* __restrict__ out, int N) {
    __shared__ __align__(16) float lsc[F], lsf[F];
    int tid = threadIdx.x;
    if (tid < F) {
        double mu = sums[tid] / (double)N_NODES;
        double var = sums[F + tid] / (double)N_NODES - mu * mu;
        if (var < 0.0) var = 0.0;
        double sc = (double)gamma[tid] / sqrt(var + BN_EPS);
        lsc[tid] = (float)sc;
        lsf[tid] = (float)((double)beta[tid] - mu * sc);
    }
    __syncthreads();
    constexpr int FV = F / 8;
    int total = N * FV;
    for (int i = blockIdx.x * 256 + tid; i < total; i += gridDim.x * 256) {
        uint4 v = h[i];
        int c4 = (i & (FV - 1)) * 2;      // float4 index of first quad
        float4 sca = ((const float4*)lsc)[c4];
        float4 scb = ((const float4*)lsc)[c4 + 1];
        float4 sfa = ((const float4*)lsf)[c4];
        float4 sfb = ((const float4*)lsf)[c4 + 1];
        float2 f0 = unpack_h2(v.x), f1 = unpack_h2(v.y);
        float2 f2 = unpack_h2(v.z), f3 = unpack_h2(v.w);
        uint4 o;
        o.x = pack_h2(fmaxf(f0.x * sca.x + sfa.x, 0.f), fmaxf(f0.y * sca.y + sfa.y, 0.f));
        o.y = pack_h2(fmaxf(f1.x * sca.z + sfa.z, 0.f), fmaxf(f1.y * sca.w + sfa.w, 0.f));
        o.z = pack_h2(fmaxf(f2.x * scb.x + sfb.x, 0.f), fmaxf(f2.y * scb.y + sfb.y, 0.f));
        o.w = pack_h2(fmaxf(f3.x * scb.z + sfb.z, 0.f), fmaxf(f3.y * scb.w + sfb.w, 0.f));
        out[i] = o;
    }
}

// ---------------- fp16 sum-gather agg, 16-deep MLP, fp32 dual-bank accum ----------------
__device__ __forceinline__ void accum8_h16(float* acc, uint4 v) {
    float2 f0 = unpack_h2(v.x), f1 = unpack_h2(v.y);
    float2 f2 = unpack_h2(v.z), f3 = unpack_h2(v.w);
    acc[0] += f0.x; acc[1] += f0.y; acc[2] += f1.x; acc[3] += f1.y;
    acc[4] += f2.x; acc[5] += f2.y; acc[6] += f3.x; acc[7] += f3.y;
}

template<int F>
__global__ __launch_bounds__(256)
void agg_sum(const uint4* __restrict__ xb, const int* __restrict__ offs,
             const int* __restrict__ oend, const int* __restrict__ nbr,
             uint4* __restrict__ aggh, int N) {
    constexpr int FV = F / 8;            // uint4 lanes per row
    constexpr int NPB = 256 / FV;        // nodes per block
    int n = blockIdx.x * NPB + threadIdx.y;
    if (n >= N) return;
    int f = threadIdx.x;
    int beg = offs[n], end = oend[n];
    float a0[8], a1[8];
#pragma unroll
    for (int q = 0; q < 8; ++q) { a0[q] = 0.f; a1[q] = 0.f; }
    int j = beg;
    // 16-deep main loop: 16 independent gathers in flight per thread
    for (; j + 16 <= end; j += 16) {
        int s[16];
#pragma unroll
        for (int u = 0; u < 16; ++u) s[u] = __builtin_nontemporal_load(nbr + j + u);
        uint4 v[16];
#pragma unroll
        for (int u = 0; u < 16; ++u) v[u] = xb[s[u] * FV + f];
#pragma unroll
        for (int u = 0; u < 16; ++u)
            accum8_h16((u & 1) ? a1 : a0, v[u]);
    }
    if (j + 8 <= end) {
        int s[8];
#pragma unroll
        for (int u = 0; u < 8; ++u) s[u] = __builtin_nontemporal_load(nbr + j + u);
        uint4 v[8];
#pragma unroll
        for (int u = 0; u < 8; ++u) v[u] = xb[s[u] * FV + f];
#pragma unroll
        for (int u = 0; u < 8; ++u)
            accum8_h16((u & 1) ? a1 : a0, v[u]);
        j += 8;
    }
    if (j + 4 <= end) {
        int s[4];
#pragma unroll
        for (int u = 0; u < 4; ++u) s[u] = __builtin_nontemporal_load(nbr + j + u);
        uint4 v[4];
#pragma unroll
        for (int u = 0; u < 4; ++u) v[u] = xb[s[u] * FV + f];
#pragma unroll
        for (int u = 0; u < 4; ++u)
            accum8_h16((u & 1) ? a1 : a0, v[u]);
        j += 4;
    }
    for (; j < end; ++j) {
        uint4 v = xb[__builtin_nontemporal_load(nbr + j) * FV + f];
        accum8_h16(a0, v);
    }
    float invd = 1.0f / fmaxf((float)(end - beg), 1.0f);
    uint4 o;
    o.x = pack_h2((a0[0] + a1[0]) * invd, (a0[1] + a1[1]) * invd);
    o.y = pack_h2((a0[2] + a1[2]) * invd, (a0[3] + a1[3]) * invd);
    o.z = pack_h2((a0[4] + a1[4]) * invd, (a0[5] + a1[5]) * invd);
    o.w = pack_h2((a0[6] + a1[6]) * invd, (a0[7] + a1[7]) * invd);
    aggh[n * FV + f] = o;
}

// ---------------- weight packing for MFMA: W -> (hi, lo) fp16 fragment order ----------------
// frag[kb][cb][lane][i] holds W[kb*32 + (lane>>4)*8 + i][cb*16 + (lane&15)].
// A-load and B-pack use the SAME (lane,i)->k map; only C/D layout matters (HW-verified).
__global__ __launch_bounds__(256)
void pack_w(const float* __restrict__ Wl2, const float* __restrict__ Wr2,
            const float* __restrict__ Wl3, const float* __restrict__ Wr3,
            __half* __restrict__ pk) {
    int e = blockIdx.x * 256 + threadIdx.x;   // grid is exactly 80*256 = 20480
    const float* W; int le, DOUT, NCB, base, SZ;
    if (e < 2048)       { W = Wl2; le = e;         DOUT = 64;  NCB = 4; base = 0;     SZ = 2048; }
    else if (e < 4096)  { W = Wr2; le = e - 2048;  DOUT = 64;  NCB = 4; base = 4096;  SZ = 2048; }
    else if (e < 12288) { W = Wl3; le = e - 4096;  DOUT = 128; NCB = 8; base = 8192;  SZ = 8192; }
    else                { W = Wr3; le = e - 12288; DOUT = 128; NCB = 8; base = 24576; SZ = 8192; }
    int i = le & 7;
    int lane = (le >> 3) & 63;
    int cbkb = le >> 9;
    int cb = cbkb % NCB;
    int kb = cbkb / NCB;
    int k = kb * 32 + ((lane >> 4) << 3) + i;
    int col = cb * 16 + (lane & 15);
    float w = W[k * DOUT + col];
    __half h = __float2half(w);
    float lo = w - __half2float(h);
    pk[base + le] = h;
    pk[base + SZ + le] = __float2half(lo);
}

// ---------------- MFMA linear: pure-load fp16 fragments (agg pre-scaled, x pre-BN'd),
// split-fp16 weights, fp32 MFMA accumulate, fp16 out, fused BN-stats partials ----------------
template<int DIN, int DOUT>
__global__ __launch_bounds__(256)
void linear_mfma(const __half* __restrict__ bnx16, const __half* __restrict__ agg16,
                 const __half* __restrict__ wlhi, const __half* __restrict__ wllo,
                 const __half* __restrict__ wrhi, const __half* __restrict__ wrlo,
                 const float* __restrict__ bl,
                 __half* __restrict__ hout16, float* __restrict__ partial, int N) {
    constexpr int KB = DIN / 32;    // K-slabs of 32
    constexpr int NCB = DOUT / 16;  // col-blocks of 16
    constexpr int MREP = 2;         // 16-row fragments per wave
    constexpr int MB = 4 * MREP * 16;  // 128 rows per block
    __shared__ float blkS[DOUT], blkQ[DOUT];
    int tid = threadIdx.x;
    for (int i = tid; i < DOUT; i += 256) { blkS[i] = 0.f; blkQ[i] = 0.f; }
    __syncthreads();
    int n0 = blockIdx.x * MB;

    int wave = tid >> 6;
    int lane = tid & 63;
    int rlane = lane & 15;
    int kg = lane >> 4;          // 0..3 -> k-group of 8
    int rbase = n0 + wave * (MREP * 16);

    // ---- A fragments: pure vector loads ----
    f16x8 aA[MREP][KB], aX[MREP][KB];
#pragma unroll
    for (int m = 0; m < MREP; ++m) {
        int row = rbase + m * 16 + rlane;
        int rowc = min(row, N - 1);
#pragma unroll
        for (int kb = 0; kb < KB; ++kb) {
            int c0 = kb * 32 + kg * 8;
            F16x8u ta, tx;
            ta.u = *(const uint4*)(agg16 + (size_t)rowc * DIN + c0);
            tx.u = *(const uint4*)(bnx16 + (size_t)rowc * DIN + c0);
            aA[m][kb] = ta.v;
            aX[m][kb] = tx.v;
        }
    }

    // ---- accumulators init with bias (D layout: row=(lane>>4)*4+r, col=lane&15) ----
    f32x4 acc[MREP][NCB];
#pragma unroll
    for (int cb = 0; cb < NCB; ++cb) {
        float bv = bl[cb * 16 + rlane];
#pragma unroll
        for (int m = 0; m < MREP; ++m)
            acc[m][cb] = {bv, bv, bv, bv};
    }

    // ---- MFMA main: acc += aA*(Wl_hi+Wl_lo) + aX*(Wr_hi+Wr_lo) ----
#pragma unroll
    for (int cb = 0; cb < NCB; ++cb) {
#pragma unroll
        for (int kb = 0; kb < KB; ++kb) {
            size_t fo = ((size_t)(kb * NCB + cb) * 64 + lane) * 8;
            f16x8 blh = *(const f16x8*)(wlhi + fo);
            f16x8 bll = *(const f16x8*)(wllo + fo);
            f16x8 brh = *(const f16x8*)(wrhi + fo);
            f16x8 brl = *(const f16x8*)(wrlo + fo);
#pragma unroll
            for (int m = 0; m < MREP; ++m) {
                acc[m][cb] = __builtin_amdgcn_mfma_f32_16x16x32_f16(aA[m][kb], blh, acc[m][cb], 0, 0, 0);
                acc[m][cb] = __builtin_amdgcn_mfma_f32_16x16x32_f16(aA[m][kb], bll, acc[m][cb], 0, 0, 0);
                acc[m][cb] = __builtin_amdgcn_mfma_f32_16x16x32_f16(aX[m][kb], brh, acc[m][cb], 0, 0, 0);
                acc[m][cb] = __builtin_amdgcn_mfma_f32_16x16x32_f16(aX[m][kb], brl, acc[m][cb], 0, 0, 0);
            }
        }
    }

    // ---- store fp16 outputs ----
#pragma unroll
    for (int m = 0; m < MREP; ++m) {
        int rowb = rbase + m * 16 + kg * 4;
#pragma unroll
        for (int r = 0; r < 4; ++r) {
            int node = rowb + r;
            if (node < N) {
#pragma unroll
                for (int cb = 0; cb < NCB; ++cb)
                    hout16[(size_t)node * DOUT + cb * 16 + rlane] = __float2half(acc[m][cb][r]);
            }
        }
    }

    // ---- fused BN-stats partials: per-block sum/sumsq per feature ----
#pragma unroll
    for (int cb = 0; cb < NCB; ++cb) {
        float s = 0.f, q = 0.f;
#pragma unroll
        for (int m = 0; m < MREP; ++m) {
            int rowb = rbase + m * 16 + kg * 4;
#pragma unroll
            for (int r = 0; r < 4; ++r) {
                if (rowb + r < N) {
                    float v = acc[m][cb][r];
                    s += v; q += v * v;
                }
            }
        }
        s += __shfl_xor(s, 16, 64); s += __shfl_xor(s, 32, 64);
        q += __shfl_xor(q, 16, 64); q += __shfl_xor(q, 32, 64);
        if (kg == 0) {
            atomicAdd(&blkS[cb * 16 + rlane], s);
            atomicAdd(&blkQ[cb * 16 + rlane], q);
        }
    }
    __syncthreads();
    float* po = partial + (size_t)blockIdx.x * (2 * DOUT);
    for (int i = tid; i < DOUT; i += 256) {
        po[i] = blkS[i];
        po[DOUT + i] = blkQ[i];
    }
}

// ---------------- stats finalize: reduce P block-partials per feature in fp64, fixed order ----------------
template<int F>
__global__ __launch_bounds__(256)
void stats_finalize2(const float* __restrict__ partial, double* __restrict__ sums, int P) {
    __shared__ double sh[256];
    int i = blockIdx.x;
    int t = threadIdx.x;
    double a = 0.0;
    for (int k = t; k < P; k += 256)
        a += (double)partial[(size_t)k * (2 * F) + i];
    sh[t] = a;
    __syncthreads();
    for (int st = 128; st > 0; st >>= 1) {
        if (t < st) sh[t] += sh[t + st];
        __syncthreads();
    }
    if (t == 0) sums[i] = sh[0];
}

// ---------------- pool (fp16 h3) with inline BN3 finalize + fused ReLU ----------------
__global__ void pool_partial(const __half* __restrict__ h, const int* __restrict__ batch,
                             const double* __restrict__ sums,
                             const float* __restrict__ gamma, const float* __restrict__ beta,
                             double* __restrict__ pooled_d, int N) {
    __shared__ float lsc[128], lsf[128];
    const int CH = 64;
    int f = threadIdx.x;
    {
        double mu = sums[f] / (double)N_NODES;
        double var = sums[128 + f] / (double)N_NODES - mu * mu;
        if (var < 0.0) var = 0.0;
        double sc = (double)gamma[f] / sqrt(var + BN_EPS);
        lsc[f] = (float)sc;
        lsf[f] = (float)((double)beta[f] - mu * sc);
    }
    __syncthreads();
    int n0 = blockIdx.x * CH;
    if (n0 >= N) return;
    int n1 = min(n0 + CH, N);
    float sc = lsc[f], sf = lsf[f];
    int g = batch[n0];
    float acc = 0.f;
    for (int n = n0; n < n1; ++n) {
        int bg = batch[n];
        if (bg != g) {
            atomicAdd(&pooled_d[g * 128 + f], (double)acc);
            acc = 0.f;
            g = bg;
        }
        float v = __half2float(h[(long long)n * 128 + f]);
        acc += fmaxf(v * sc + sf, 0.f);
    }
    atomicAdd(&pooled_d[g * 128 + f], (double)acc);
}

// ---------------- fused pool-finalize + head MLP ----------------
__global__ void mlp_fused(const double* __restrict__ pooled_d, const int* __restrict__ batch,
                          const float* __restrict__ Wf1, const float* __restrict__ bf1,
                          const float* __restrict__ Wf2, const float* __restrict__ bf2,
                          float* __restrict__ out, int N) {
    __shared__ float sp[128];
    int g = blockIdx.x;
    int t = threadIdx.x;
    int lo = 0, hi = N;
    while (lo < hi) { int m = (lo + hi) >> 1; if (batch[m] < g) lo = m + 1; else hi = m; }
    int start = lo;
    hi = N;
    while (lo < hi) { int m = (lo + hi) >> 1; if (batch[m] < g + 1) lo = m + 1; else hi = m; }
    int cnt = lo - start;
    sp[t] = (float)(pooled_d[g * 128 + t] / (double)max(cnt, 1));
    __syncthreads();
    if (t < 64) {
        float hacc = bf1[t];
#pragma unroll 8
        for (int k = 0; k < 128; ++k) hacc += sp[k] * Wf1[k * 64 + t];
        hacc = fmaxf(hacc, 0.f) * Wf2[t];
        for (int o = 32; o > 0; o >>= 1) hacc += __shfl_down(hacc, o);
        if (t == 0) out[g] = hacc + bf2[0];
    }
}

extern "C" void kernel_launch(void* const* d_in, const int* in_sizes, int n_in,
                              void* d_out, int out_size, void* d_ws, size_t ws_size,
                              hipStream_t stream) {
    const float* x     = (const float*)d_in[0];
    const int*   ei    = (const int*)d_in[1];
    const int*   batch = (const int*)d_in[2];
    const float *Wl1=(const float*)d_in[3],  *bl1=(const float*)d_in[4],  *Wr1=(const float*)d_in[5];
    const float *g1 =(const float*)d_in[6],  *be1=(const float*)d_in[7];
    const float *Wl2=(const float*)d_in[8],  *bl2=(const float*)d_in[9],  *Wr2=(const float*)d_in[10];
    const float *g2 =(const float*)d_in[11], *be2=(const float*)d_in[12];
    const float *Wl3=(const float*)d_in[13], *bl3=(const float*)d_in[14], *Wr3=(const float*)d_in[15];
    const float *g3 =(const float*)d_in[16], *be3=(const float*)d_in[17];
    const float *Wf1=(const float*)d_in[18], *bf1=(const float*)d_in[19];
    const float *Wf2=(const float*)d_in[20], *bf2=(const float*)d_in[21];

    const int N = N_NODES;
    const int E = in_sizes[1] / 2;
    const int* src = ei;
    const int* dst = ei + E;

    char* ws = (char*)d_ws;
    size_t off = 0;
    auto salloc = [&](size_t bytes) {
        void* p = ws + off;
        off += (bytes + 255) & ~(size_t)255;
        return p;
    };
    // --- zero-init region (one memset) ---
    double* sums    = (double*)salloc(768 * 8);
    double* pooledd = (double*)salloc((size_t)N_GRAPHS * 128 * 8);
    size_t zero_bytes = off;
    // --- rest ---
    int*    offs    = (int*)   salloc((size_t)N * 4);
    int*    oend    = (int*)   salloc((size_t)N * 4);
    int*    fcur    = (int*)   salloc(784 * 4);
    int*    ccur    = (int*)   salloc(NC * 4);
    int*    nbr     = (int*)   salloc((size_t)NB * CAPF * 4);        // 9.6 MB (padded fine regions)
    float*  partial = (float*) salloc((size_t)1024 * 256 * 4);       // 1 MB (stats partials)
    __half* pk      = (__half*)salloc((size_t)40960 * 2);            // 80 KB packed weights
    __half* h1h     = (__half*)salloc((size_t)(N + 256) * 32 * 2);   // 6.4 MB
    __half* b1h     = (__half*)salloc((size_t)(N + 256) * 32 * 2);   // 6.4 MB bnrelu(h1)
    __half* h2h     = (__half*)salloc((size_t)(N + 256) * 64 * 2);   // 12.8 MB (hosts qsrc early)
    __half* b2h     = (__half*)salloc((size_t)(N + 256) * 64 * 2);   // 12.8 MB bnrelu(h2)
    __half* h3h     = (__half*)salloc((size_t)(N + 256) * 128 * 2);  // 25.7 MB (hosts cdst/csrc early)
    __half* aggh    = (__half*)salloc((size_t)(N + 256) * 64 * 2);   // 12.8 MB (hosts qdst early)
    (void)ws_size;

    double* sums1 = sums, *sums2 = sums + 256, *sums3 = sums + 512;
    int* cdst = (int*)h3h;                 // 49*CAPC = 7.2 MB
    int* csrc = cdst + (size_t)NC * CAPC;  // 7.2 MB (total 14.4 <= 25.7)
    int* qdst = (int*)aggh;                // 782*CAPF = 9.6 MB <= 12.8
    int* qsrc = (int*)h2h;                 // 9.6 MB <= 12.8

    const __half *pwl2h = pk,         *pwl2l = pk + 2048;
    const __half *pwr2h = pk + 4096,  *pwr2l = pk + 6144;
    const __half *pwl3h = pk + 8192,  *pwl3l = pk + 16384;
    const __half *pwr3h = pk + 24576, *pwr3l = pk + 32768;

    hipMemsetAsync(sums, 0, zero_bytes, stream);

    // ---- weight packing + cursor init (tiny) ----
    pack_w<<<80, 256, 0, stream>>>(Wl2, Wr2, Wl3, Wr3, pk);
    cur_init<<<1, 1024, 0, stream>>>(ccur, fcur);

    // ---- CSR build: fixed-capacity buckets, no histogram/scan passes ----
    part1<<<(E + PT1 - 1) / PT1, 256, 0, stream>>>(dst, src, ccur, cdst, csrc, E);
    part2<<<NC * BPC, 256, 0, stream>>>(cdst, csrc, ccur, fcur, qdst, qsrc);
    fill_final<<<NB, 256, 0, stream>>>(qdst, qsrc, fcur, offs, oend, nbr, N);

    const int NL = (N + 255) / 256;
    const int NBLK = (N + 127) / 128;   // 782 blocks for linear_mfma

    // ---- layer 1: fused agg + linear + stats -> fp16 h1 ----
    layer1_fused<<<NL, 256, 0, stream>>>((const float2*)x, offs, oend, nbr,
                                          Wl1, bl1, Wr1, h1h, sums1, N);

    // ---- layer 2 ----
    bn_apply<32><<<512, 256, 0, stream>>>((const uint4*)h1h, sums1, g1, be1, (uint4*)b1h, N);
    agg_sum<32><<<(N + 63) / 64, dim3(4, 64), 0, stream>>>(
        (const uint4*)b1h, offs, oend, nbr, (uint4*)aggh, N);
    linear_mfma<32, 64><<<NBLK, 256, 0, stream>>>(
        b1h, (const __half*)aggh, pwl2h, pwl2l, pwr2h, pwr2l, bl2, h2h, partial, N);
    stats_finalize2<64><<<128, 256, 0, stream>>>(partial, sums2, NBLK);

    // ---- layer 3 ----
    bn_apply<64><<<512, 256, 0, stream>>>((const uint4*)h2h, sums2, g2, be2, (uint4*)b2h, N);
    agg_sum<64><<<(N + 31) / 32, dim3(8, 32), 0, stream>>>(
        (const uint4*)b2h, offs, oend, nbr, (uint4*)aggh, N);
    linear_mfma<64, 128><<<NBLK, 256, 0, stream>>>(
        b2h, (const __half*)aggh, pwl3h, pwl3l, pwr3h, pwr3l, bl3, h3h, partial, N);
    stats_finalize2<128><<<256, 256, 0, stream>>>(partial, sums3, NBLK);

    // ---- pool + head ----
    pool_partial<<<(N + 63) / 64, 128, 0, stream>>>(h3h, batch, sums3, g3, be3, pooledd, N);
    mlp_fused<<<N_GRAPHS, 128, 0, stream>>>(pooledd, batch, Wf1, bf1, Wf2, bf2, (float*)d_out, N);
}

// Round 12
// 307.389 us; speedup vs baseline: 1.4438x; 1.0163x over previous
//
#include <hip/hip_runtime.h>
#include <hip/hip_fp16.h>

#define N_NODES 100000
#define N_GRAPHS 64
#define BN_EPS 1e-5

#define NB 782
#define NC 49
#define PT1 4096
#define PT2 2048
#define BPC 16
#define CAP 3072
#define CAPC 36864   // fixed coarse-bucket capacity (mean 32768, sigma~181 -> 22 sigma margin)
#define CAPF 3072    // fixed fine-bucket capacity (mean 2046)

typedef _Float16 f16x8 __attribute__((ext_vector_type(8)));
typedef float f32x4 __attribute__((ext_vector_type(4)));

union F16x8u {
    f16x8 v;
    __half2 h2[4];
    uint4 u;
};

__device__ __forceinline__ float bfly64(float v) {
#pragma unroll
    for (int m = 1; m < 64; m <<= 1) v += __shfl_xor(v, m, 64);
    return v;
}

__device__ __forceinline__ unsigned pack_h2(float a, float b) {
    __half2 h = __floats2half2_rn(a, b);
    unsigned w;
    __builtin_memcpy(&w, &h, 4);
    return w;
}

__device__ __forceinline__ float2 unpack_h2(unsigned w) {
    __half2 h;
    __builtin_memcpy(&h, &w, 4);
    return __half22float2(h);
}

// ---------------- weight packing for MFMA + cursor init (fused) ----------------
// frag[kb][cb][lane][i] holds W[kb*32 + (lane>>4)*8 + i][cb*16 + (lane&15)].
__global__ __launch_bounds__(256)
void pack_w(const float* __restrict__ Wl2, const float* __restrict__ Wr2,
            const float* __restrict__ Wl3, const float* __restrict__ Wr3,
            __half* __restrict__ pk, int* __restrict__ ccur, int* __restrict__ fcur) {
    int tid = threadIdx.x;
    if (blockIdx.x == 0) {
        for (int t = tid; t < NC; t += 256) ccur[t] = t * CAPC;
        for (int t = tid; t < 784; t += 256) fcur[t] = t * CAPF;
    }
    int e = blockIdx.x * 256 + tid;   // grid is exactly 80*256 = 20480
    const float* W; int le, DOUT, NCB, base, SZ;
    if (e < 2048)       { W = Wl2; le = e;         DOUT = 64;  NCB = 4; base = 0;     SZ = 2048; }
    else if (e < 4096)  { W = Wr2; le = e - 2048;  DOUT = 64;  NCB = 4; base = 4096;  SZ = 2048; }
    else if (e < 12288) { W = Wl3; le = e - 4096;  DOUT = 128; NCB = 8; base = 8192;  SZ = 8192; }
    else                { W = Wr3; le = e - 12288; DOUT = 128; NCB = 8; base = 24576; SZ = 8192; }
    int i = le & 7;
    int lane = (le >> 3) & 63;
    int cbkb = le >> 9;
    int cb = cbkb % NCB;
    int kb = cbkb / NCB;
    int k = kb * 32 + ((lane >> 4) << 3) + i;
    int col = cb * 16 + (lane & 15);
    float w = W[k * DOUT + col];
    __half h = __float2half(w);
    float lo = w - __half2float(h);
    pk[base + le] = h;
    pk[base + SZ + le] = __float2half(lo);
}

// Packed edge word: bits 0..16 = src (N < 2^17), bits 17..27 = dst & 2047.
// Coarse bucket id (dst >> 11) is implied by the region the word lives in.
// fine idx = (p >> 24) & 15   [= (dst >> 7) & 15]
// local node = (p >> 17) & 127 [= dst & 127]

// ---------------- pass 1: coarse partition -> packed words ----------------
__global__ __launch_bounds__(256)
void part1(const int* __restrict__ dst, const int* __restrict__ src,
           int* __restrict__ ccur, int* __restrict__ cpk, int E) {
    __shared__ int ld[PT1];
    __shared__ unsigned char lb[PT1];
    __shared__ int hist[NC], lbase[NC], gbase[NC];
    long long t0 = (long long)blockIdx.x * PT1;
    int n = (int)min((long long)PT1, (long long)E - t0);
    int tid = threadIdx.x;
    for (int i = tid; i < NC; i += 256) hist[i] = 0;
    __syncthreads();
    int p[PT1 / 256], c[PT1 / 256];
#pragma unroll
    for (int k = 0; k < PT1 / 256; ++k) {
        int li = k * 256 + tid;
        if (li < n) {
            int d = __builtin_nontemporal_load(dst + t0 + li);
            int s = __builtin_nontemporal_load(src + t0 + li);
            c[k] = d >> 11;
            p[k] = ((d & 2047) << 17) | s;
            atomicAdd(&hist[c[k]], 1);
        }
    }
    __syncthreads();
    if (tid == 0) {
        int run = 0;
        for (int i = 0; i < NC; ++i) { lbase[i] = run; run += hist[i]; }
    }
    __syncthreads();
    if (tid < NC) gbase[tid] = atomicAdd(&ccur[tid], hist[tid]);
    __syncthreads();
    for (int i = tid; i < NC; i += 256) hist[i] = 0;
    __syncthreads();
#pragma unroll
    for (int k = 0; k < PT1 / 256; ++k) {
        int li = k * 256 + tid;
        if (li < n) {
            int pos = lbase[c[k]] + atomicAdd(&hist[c[k]], 1);
            ld[pos] = p[k]; lb[pos] = (unsigned char)c[k];
        }
    }
    __syncthreads();
    for (int i = tid; i < n; i += 256) {
        int bb = lb[i];
        int g = gbase[bb] + (i - lbase[bb]);
        cpk[g] = ld[i];
    }
}

// ---------------- pass 2: fine partition (packed words) ----------------
__global__ __launch_bounds__(256)
void part2(const int* __restrict__ cpk, const int* __restrict__ ccur,
           int* __restrict__ fcur, int* __restrict__ qpk) {
    __shared__ int ld[PT2];
    __shared__ unsigned char lb[PT2];
    __shared__ int hist[16], lbase[16], gbase[16];
    int c = blockIdx.x / BPC;
    int j = blockIdx.x % BPC;
    int beg = c * CAPC;
    int end = ccur[c];          // final cursor = base + count
    int tid = threadIdx.x;
    for (int t0 = beg + j * PT2; t0 < end; t0 += BPC * PT2) {
        int n = min(PT2, end - t0);
        if (tid < 16) hist[tid] = 0;
        __syncthreads();
        int p[PT2 / 256], f[PT2 / 256];
#pragma unroll
        for (int k = 0; k < PT2 / 256; ++k) {
            int li = k * 256 + tid;
            if (li < n) {
                p[k] = cpk[t0 + li];
                f[k] = (p[k] >> 24) & 15;
                atomicAdd(&hist[f[k]], 1);
            }
        }
        __syncthreads();
        if (tid == 0) {
            int run = 0;
            for (int i = 0; i < 16; ++i) { lbase[i] = run; run += hist[i]; }
        }
        __syncthreads();
        if (tid < 16) gbase[tid] = atomicAdd(&fcur[(c << 4) + tid], hist[tid]);
        __syncthreads();
        if (tid < 16) hist[tid] = 0;
        __syncthreads();
#pragma unroll
        for (int k = 0; k < PT2 / 256; ++k) {
            int li = k * 256 + tid;
            if (li < n) {
                int pos = lbase[f[k]] + atomicAdd(&hist[f[k]], 1);
                ld[pos] = p[k]; lb[pos] = (unsigned char)f[k];
            }
        }
        __syncthreads();
        for (int i = tid; i < n; i += 256) {
            int bb = lb[i];
            int g = gbase[bb] + (i - lbase[bb]);
            qpk[g] = ld[i];
        }
        __syncthreads();
    }
}

// ---------------- pass 3: per-bucket CSR finalize (emits beg + end arrays) ----------------
__global__ __launch_bounds__(256)
void fill_final(const int* __restrict__ qpk, const int* __restrict__ fcur,
                int* __restrict__ offs, int* __restrict__ oend,
                int* __restrict__ nbr, int N) {
    __shared__ int cnt[128], cbase[128], cur[128];
    __shared__ int lout[CAP];
    int b = blockIdx.x;
    int nlo = b << 7;
    int nn = min(128, N - nlo);
    int ebeg = b * CAPF;
    int ne = fcur[b] - ebeg;    // final cursor - base = count
    int tid = threadIdx.x;
    if (tid < 128) { cnt[tid] = 0; cur[tid] = 0; }
    __syncthreads();
    for (int i = tid; i < ne; i += 256)
        atomicAdd(&cnt[(qpk[ebeg + i] >> 17) & 127], 1);
    __syncthreads();
    if (tid < 128) cbase[tid] = cnt[tid];
    __syncthreads();
    for (int st = 1; st < 128; st <<= 1) {
        int v = 0;
        if (tid < 128 && tid >= st) v = cbase[tid - st];
        __syncthreads();
        if (tid < 128 && tid >= st) cbase[tid] += v;
        __syncthreads();
    }
    if (tid < nn) {
        offs[nlo + tid] = ebeg + (tid ? cbase[tid - 1] : 0);
        oend[nlo + tid] = ebeg + cbase[tid];
    }
    __syncthreads();
    for (int i = tid; i < ne; i += 256) {
        int p = qpk[ebeg + i];
        int ln = (p >> 17) & 127;
        int pos = (ln ? cbase[ln - 1] : 0) + atomicAdd(&cur[ln], 1);
        lout[pos] = p & 0x1FFFF;
    }
    __syncthreads();
    for (int i = tid; i < ne; i += 256)
        nbr[ebeg + i] = lout[i];
}

// ---------------- layer 1 fused: agg + linear + BN stats; fp16 h1 out ----------------
__global__ __launch_bounds__(256)
void layer1_fused(const float2* __restrict__ x2,
                  const int* __restrict__ offs, const int* __restrict__ oend,
                  const int* __restrict__ nbr,
                  const float* __restrict__ Wl, const float* __restrict__ bl,
                  const float* __restrict__ Wr,
                  __half* __restrict__ hout16,
                  double* __restrict__ sums, int N) {
    __shared__ float sAr[64];
    int tid = threadIdx.x;
    if (tid < 64) sAr[tid] = 0.f;
    __syncthreads();
    int n = blockIdx.x * 256 + tid;
    bool valid = (n < N);
    int beg = 0, end = 0;
    if (valid) { beg = offs[n]; end = oend[n]; }
    float ax0 = 0.f, ay0 = 0.f, ax1 = 0.f, ay1 = 0.f;
    int j = beg;
    for (; j + 16 <= end; j += 16) {
        int s[16];
#pragma unroll
        for (int u = 0; u < 16; ++u) s[u] = __builtin_nontemporal_load(nbr + j + u);
        float2 v[16];
#pragma unroll
        for (int u = 0; u < 16; ++u) v[u] = x2[s[u]];
#pragma unroll
        for (int u = 0; u < 16; ++u) {
            if (u & 1) { ax1 += v[u].x; ay1 += v[u].y; }
            else       { ax0 += v[u].x; ay0 += v[u].y; }
        }
    }
    for (; j + 4 <= end; j += 4) {
        int s[4];
#pragma unroll
        for (int u = 0; u < 4; ++u) s[u] = __builtin_nontemporal_load(nbr + j + u);
        float2 v[4];
#pragma unroll
        for (int u = 0; u < 4; ++u) v[u] = x2[s[u]];
        ax0 += v[0].x; ay0 += v[0].y;
        ax1 += v[1].x; ay1 += v[1].y;
        ax0 += v[2].x; ay0 += v[2].y;
        ax1 += v[3].x; ay1 += v[3].y;
    }
    for (; j < end; ++j) {
        float2 v = x2[nbr[j]];
        ax0 += v.x; ay0 += v.y;
    }
    float invd = 1.0f / fmaxf((float)(end - beg), 1.0f);
    float a0 = (ax0 + ax1) * invd, a1 = (ay0 + ay1) * invd;
    float x0 = 0.f, x1 = 0.f;
    if (valid) {
        float2 xv = x2[n];
        x0 = xv.x; x1 = xv.y;
    }
    float acc[32];
#pragma unroll
    for (int jj = 0; jj < 32; ++jj)
        acc[jj] = bl[jj] + a0 * Wl[jj] + a1 * Wl[32 + jj] + x0 * Wr[jj] + x1 * Wr[32 + jj];
    if (valid) {
        unsigned w[16];
#pragma unroll
        for (int p = 0; p < 16; ++p) w[p] = pack_h2(acc[2*p], acc[2*p+1]);
        uint4* q = (uint4*)(hout16 + (size_t)n * 32);
        q[0] = make_uint4(w[0], w[1], w[2], w[3]);
        q[1] = make_uint4(w[4], w[5], w[6], w[7]);
        q[2] = make_uint4(w[8], w[9], w[10], w[11]);
        q[3] = make_uint4(w[12], w[13], w[14], w[15]);
    }
    int lane = tid & 63;
#pragma unroll
    for (int jj = 0; jj < 32; ++jj) {
        float v = valid ? acc[jj] : 0.f;
        float s = bfly64(v);
        float q = bfly64(v * v);
        if (lane == jj) atomicAdd(&sAr[jj], s);
        if (lane == 32 + jj) atomicAdd(&sAr[32 + jj], q);
    }
    __syncthreads();
    if (tid < 64) atomicAdd(&sums[tid], (double)sAr[tid]);
}

// ---------------- per-node BN+ReLU apply: h -> b (fp16), once per node ----------------
template<int F>
__global__ __launch_bounds__(256)
void bn_apply(const uint4* __restrict__ h, const double* __restrict__ sums,
              const float* __restrict__ gamma, const float* __restrict__ beta,
              uint4* __restrict__ out, int N) {
    __shared__ __align__(16) float lsc[F], lsf[F];
    int tid = threadIdx.x;
    if (tid < F) {
        double mu = sums[tid] / (double)N_NODES;
        double var = sums[F + tid] / (double)N_NODES - mu * mu;
        if (var < 0.0) var = 0.0;
        double sc = (double)gamma[tid] / sqrt(var + BN_EPS);
        lsc[tid] = (float)sc;
        lsf[tid] = (float)((double)beta[tid] - mu * sc);
    }
    __syncthreads();
    constexpr int FV = F / 8;
    int total = N * FV;
    for (int i = blockIdx.x * 256 + tid; i < total; i += gridDim.x * 256) {
        uint4 v = h[i];
        int c4 = (i & (FV - 1)) * 2;      // float4 index of first quad
        float4 sca = ((const float4*)lsc)[c4];
        float4 scb = ((const float4*)lsc)[c4 + 1];
        float4 sfa = ((const float4*)lsf)[c4];
        float4 sfb = ((const float4*)lsf)[c4 + 1];
        float2 f0 = unpack_h2(v.x), f1 = unpack_h2(v.y);
        float2 f2 = unpack_h2(v.z), f3 = unpack_h2(v.w);
        uint4 o;
        o.x = pack_h2(fmaxf(f0.x * sca.x + sfa.x, 0.f), fmaxf(f0.y * sca.y + sfa.y, 0.f));
        o.y = pack_h2(fmaxf(f1.x * sca.z + sfa.z, 0.f), fmaxf(f1.y * sca.w + sfa.w, 0.f));
        o.z = pack_h2(fmaxf(f2.x * scb.x + sfb.x, 0.f), fmaxf(f2.y * scb.y + sfb.y, 0.f));
        o.w = pack_h2(fmaxf(f3.x * scb.z + sfb.z, 0.f), fmaxf(f3.y * scb.w + sfb.w, 0.f));
        out[i] = o;
    }
}

// ---------------- fp16 sum-gather agg, 16-deep MLP, fp32 dual-bank accum ----------------
__device__ __forceinline__ void accum8_h16(float* acc, uint4 v) {
    float2 f0 = unpack_h2(v.x), f1 = unpack_h2(v.y);
    float2 f2 = unpack_h2(v.z), f3 = unpack_h2(v.w);
    acc[0] += f0.x; acc[1] += f0.y; acc[2] += f1.x; acc[3] += f1.y;
    acc[4] += f2.x; acc[5] += f2.y; acc[6] += f3.x; acc[7] += f3.y;
}

template<int F>
__global__ __launch_bounds__(256)
void agg_sum(const uint4* __restrict__ xb, const int* __restrict__ offs,
             const int* __restrict__ oend, const int* __restrict__ nbr,
             uint4* __restrict__ aggh, int N) {
    constexpr int FV = F / 8;            // uint4 lanes per row
    constexpr int NPB = 256 / FV;        // nodes per block
    int n = blockIdx.x * NPB + threadIdx.y;
    if (n >= N) return;
    int f = threadIdx.x;
    int beg = offs[n], end = oend[n];
    float a0[8], a1[8];
#pragma unroll
    for (int q = 0; q < 8; ++q) { a0[q] = 0.f; a1[q] = 0.f; }
    int j = beg;
    // 16-deep main loop: 16 independent gathers in flight per thread
    for (; j + 16 <= end; j += 16) {
        int s[16];
#pragma unroll
        for (int u = 0; u < 16; ++u) s[u] = __builtin_nontemporal_load(nbr + j + u);
        uint4 v[16];
#pragma unroll
        for (int u = 0; u < 16; ++u) v[u] = xb[s[u] * FV + f];
#pragma unroll
        for (int u = 0; u < 16; ++u)
            accum8_h16((u & 1) ? a1 : a0, v[u]);
    }
    if (j + 8 <= end) {
        int s[8];
#pragma unroll
        for (int u = 0; u < 8; ++u) s[u] = __builtin_nontemporal_load(nbr + j + u);
        uint4 v[8];
#pragma unroll
        for (int u = 0; u < 8; ++u) v[u] = xb[s[u] * FV + f];
#pragma unroll
        for (int u = 0; u < 8; ++u)
            accum8_h16((u & 1) ? a1 : a0, v[u]);
        j += 8;
    }
    if (j + 4 <= end) {
        int s[4];
#pragma unroll
        for (int u = 0; u < 4; ++u) s[u] = __builtin_nontemporal_load(nbr + j + u);
        uint4 v[4];
#pragma unroll
        for (int u = 0; u < 4; ++u) v[u] = xb[s[u] * FV + f];
#pragma unroll
        for (int u = 0; u < 4; ++u)
            accum8_h16((u & 1) ? a1 : a0, v[u]);
        j += 4;
    }
    for (; j < end; ++j) {
        uint4 v = xb[__builtin_nontemporal_load(nbr + j) * FV + f];
        accum8_h16(a0, v);
    }
    float invd = 1.0f / fmaxf((float)(end - beg), 1.0f);
    uint4 o;
    o.x = pack_h2((a0[0] + a1[0]) * invd, (a0[1] + a1[1]) * invd);
    o.y = pack_h2((a0[2] + a1[2]) * invd, (a0[3] + a1[3]) * invd);
    o.z = pack_h2((a0[4] + a1[4]) * invd, (a0[5] + a1[5]) * invd);
    o.w = pack_h2((a0[6] + a1[6]) * invd, (a0[7] + a1[7]) * invd);
    aggh[n * FV + f] = o;
}

// ---------------- MFMA linear: pure-load fp16 fragments (agg pre-scaled, x pre-BN'd),
// split-fp16 weights, fp32 MFMA accumulate, fp16 out, fused BN-stats partials ----------------
template<int DIN, int DOUT>
__global__ __launch_bounds__(256)
void linear_mfma(const __half* __restrict__ bnx16, const __half* __restrict__ agg16,
                 const __half* __restrict__ wlhi, const __half* __restrict__ wllo,
                 const __half* __restrict__ wrhi, const __half* __restrict__ wrlo,
                 const float* __restrict__ bl,
                 __half* __restrict__ hout16, float* __restrict__ partial, int N) {
    constexpr int KB = DIN / 32;    // K-slabs of 32
    constexpr int NCB = DOUT / 16;  // col-blocks of 16
    constexpr int MREP = 2;         // 16-row fragments per wave
    constexpr int MB = 4 * MREP * 16;  // 128 rows per block
    __shared__ float blkS[DOUT], blkQ[DOUT];
    int tid = threadIdx.x;
    for (int i = tid; i < DOUT; i += 256) { blkS[i] = 0.f; blkQ[i] = 0.f; }
    __syncthreads();
    int n0 = blockIdx.x * MB;

    int wave = tid >> 6;
    int lane = tid & 63;
    int rlane = lane & 15;
    int kg = lane >> 4;          // 0..3 -> k-group of 8
    int rbase = n0 + wave * (MREP * 16);

    // ---- A fragments: pure vector loads ----
    f16x8 aA[MREP][KB], aX[MREP][KB];
#pragma unroll
    for (int m = 0; m < MREP; ++m) {
        int row = rbase + m * 16 + rlane;
        int rowc = min(row, N - 1);
#pragma unroll
        for (int kb = 0; kb < KB; ++kb) {
            int c0 = kb * 32 + kg * 8;
            F16x8u ta, tx;
            ta.u = *(const uint4*)(agg16 + (size_t)rowc * DIN + c0);
            tx.u = *(const uint4*)(bnx16 + (size_t)rowc * DIN + c0);
            aA[m][kb] = ta.v;
            aX[m][kb] = tx.v;
        }
    }

    // ---- accumulators init with bias (D layout: row=(lane>>4)*4+r, col=lane&15) ----
    f32x4 acc[MREP][NCB];
#pragma unroll
    for (int cb = 0; cb < NCB; ++cb) {
        float bv = bl[cb * 16 + rlane];
#pragma unroll
        for (int m = 0; m < MREP; ++m)
            acc[m][cb] = {bv, bv, bv, bv};
    }

    // ---- MFMA main: acc += aA*(Wl_hi+Wl_lo) + aX*(Wr_hi+Wr_lo) ----
#pragma unroll
    for (int cb = 0; cb < NCB; ++cb) {
#pragma unroll
        for (int kb = 0; kb < KB; ++kb) {
            size_t fo = ((size_t)(kb * NCB + cb) * 64 + lane) * 8;
            f16x8 blh = *(const f16x8*)(wlhi + fo);
            f16x8 bll = *(const f16x8*)(wllo + fo);
            f16x8 brh = *(const f16x8*)(wrhi + fo);
            f16x8 brl = *(const f16x8*)(wrlo + fo);
#pragma unroll
            for (int m = 0; m < MREP; ++m) {
                acc[m][cb] = __builtin_amdgcn_mfma_f32_16x16x32_f16(aA[m][kb], blh, acc[m][cb], 0, 0, 0);
                acc[m][cb] = __builtin_amdgcn_mfma_f32_16x16x32_f16(aA[m][kb], bll, acc[m][cb], 0, 0, 0);
                acc[m][cb] = __builtin_amdgcn_mfma_f32_16x16x32_f16(aX[m][kb], brh, acc[m][cb], 0, 0, 0);
                acc[m][cb] = __builtin_amdgcn_mfma_f32_16x16x32_f16(aX[m][kb], brl, acc[m][cb], 0, 0, 0);
            }
        }
    }

    // ---- store fp16 outputs ----
#pragma unroll
    for (int m = 0; m < MREP; ++m) {
        int rowb = rbase + m * 16 + kg * 4;
#pragma unroll
        for (int r = 0; r < 4; ++r) {
            int node = rowb + r;
            if (node < N) {
#pragma unroll
                for (int cb = 0; cb < NCB; ++cb)
                    hout16[(size_t)node * DOUT + cb * 16 + rlane] = __float2half(acc[m][cb][r]);
            }
        }
    }

    // ---- fused BN-stats partials: per-block sum/sumsq per feature ----
#pragma unroll
    for (int cb = 0; cb < NCB; ++cb) {
        float s = 0.f, q = 0.f;
#pragma unroll
        for (int m = 0; m < MREP; ++m) {
            int rowb = rbase + m * 16 + kg * 4;
#pragma unroll
            for (int r = 0; r < 4; ++r) {
                if (rowb + r < N) {
                    float v = acc[m][cb][r];
                    s += v; q += v * v;
                }
            }
        }
        s += __shfl_xor(s, 16, 64); s += __shfl_xor(s, 32, 64);
        q += __shfl_xor(q, 16, 64); q += __shfl_xor(q, 32, 64);
        if (kg == 0) {
            atomicAdd(&blkS[cb * 16 + rlane], s);
            atomicAdd(&blkQ[cb * 16 + rlane], q);
        }
    }
    __syncthreads();
    float* po = partial + (size_t)blockIdx.x * (2 * DOUT);
    for (int i = tid; i < DOUT; i += 256) {
        po[i] = blkS[i];
        po[DOUT + i] = blkQ[i];
    }
}

// ---------------- stats finalize: reduce P block-partials per feature in fp64, fixed order ----------------
template<int F>
__global__ __launch_bounds__(256)
void stats_finalize2(const float* __restrict__ partial, double* __restrict__ sums, int P) {
    __shared__ double sh[256];
    int i = blockIdx.x;
    int t = threadIdx.x;
    double a = 0.0;
    for (int k = t; k < P; k += 256)
        a += (double)partial[(size_t)k * (2 * F) + i];
    sh[t] = a;
    __syncthreads();
    for (int st = 128; st > 0; st >>= 1) {
        if (t < st) sh[t] += sh[t + st];
        __syncthreads();
    }
    if (t == 0) sums[i] = sh[0];
}

// ---------------- pool (fp16 h3) with inline BN3 finalize + fused ReLU ----------------
__global__ void pool_partial(const __half* __restrict__ h, const int* __restrict__ batch,
                             const double* __restrict__ sums,
                             const float* __restrict__ gamma, const float* __restrict__ beta,
                             double* __restrict__ pooled_d, int N) {
    __shared__ float lsc[128], lsf[128];
    const int CH = 64;
    int f = threadIdx.x;
    {
        double mu = sums[f] / (double)N_NODES;
        double var = sums[128 + f] / (double)N_NODES - mu * mu;
        if (var < 0.0) var = 0.0;
        double sc = (double)gamma[f] / sqrt(var + BN_EPS);
        lsc[f] = (float)sc;
        lsf[f] = (float)((double)beta[f] - mu * sc);
    }
    __syncthreads();
    int n0 = blockIdx.x * CH;
    if (n0 >= N) return;
    int n1 = min(n0 + CH, N);
    float sc = lsc[f], sf = lsf[f];
    int g = batch[n0];
    float acc = 0.f;
    for (int n = n0; n < n1; ++n) {
        int bg = batch[n];
        if (bg != g) {
            atomicAdd(&pooled_d[g * 128 + f], (double)acc);
            acc = 0.f;
            g = bg;
        }
        float v = __half2float(h[(long long)n * 128 + f]);
        acc += fmaxf(v * sc + sf, 0.f);
    }
    atomicAdd(&pooled_d[g * 128 + f], (double)acc);
}

// ---------------- fused pool-finalize + head MLP ----------------
__global__ void mlp_fused(const double* __restrict__ pooled_d, const int* __restrict__ batch,
                          const float* __restrict__ Wf1, const float* __restrict__ bf1,
                          const float* __restrict__ Wf2, const float* __restrict__ bf2,
                          float* __restrict__ out, int N) {
    __shared__ float sp[128];
    int g = blockIdx.x;
    int t = threadIdx.x;
    int lo = 0, hi = N;
    while (lo < hi) { int m = (lo + hi) >> 1; if (batch[m] < g) lo = m + 1; else hi = m; }
    int start = lo;
    hi = N;
    while (lo < hi) { int m = (lo + hi) >> 1; if (batch[m] < g + 1) lo = m + 1; else hi = m; }
    int cnt = lo - start;
    sp[t] = (float)(pooled_d[g * 128 + t] / (double)max(cnt, 1));
    __syncthreads();
    if (t < 64) {
        float hacc = bf1[t];
#pragma unroll 8
        for (int k = 0; k < 128; ++k) hacc += sp[k] * Wf1[k * 64 + t];
        hacc = fmaxf(hacc, 0.f) * Wf2[t];
        for (int o = 32; o > 0; o >>= 1) hacc += __shfl_down(hacc, o);
        if (t == 0) out[g] = hacc + bf2[0];
    }
}

extern "C" void kernel_launch(void* const* d_in, const int* in_sizes, int n_in,
                              void* d_out, int out_size, void* d_ws, size_t ws_size,
                              hipStream_t stream) {
    const float* x     = (const float*)d_in[0];
    const int*   ei    = (const int*)d_in[1];
    const int*   batch = (const int*)d_in[2];
    const float *Wl1=(const float*)d_in[3],  *bl1=(const float*)d_in[4],  *Wr1=(const float*)d_in[5];
    const float *g1 =(const float*)d_in[6],  *be1=(const float*)d_in[7];
    const float *Wl2=(const float*)d_in[8],  *bl2=(const float*)d_in[9],  *Wr2=(const float*)d_in[10];
    const float *g2 =(const float*)d_in[11], *be2=(const float*)d_in[12];
    const float *Wl3=(const float*)d_in[13], *bl3=(const float*)d_in[14], *Wr3=(const float*)d_in[15];
    const float *g3 =(const float*)d_in[16], *be3=(const float*)d_in[17];
    const float *Wf1=(const float*)d_in[18], *bf1=(const float*)d_in[19];
    const float *Wf2=(const float*)d_in[20], *bf2=(const float*)d_in[21];

    const int N = N_NODES;
    const int E = in_sizes[1] / 2;
    const int* src = ei;
    const int* dst = ei + E;

    char* ws = (char*)d_ws;
    size_t off = 0;
    auto salloc = [&](size_t bytes) {
        void* p = ws + off;
        off += (bytes + 255) & ~(size_t)255;
        return p;
    };
    // --- zero-init region (one memset) ---
    double* sums    = (double*)salloc(768 * 8);
    double* pooledd = (double*)salloc((size_t)N_GRAPHS * 128 * 8);
    size_t zero_bytes = off;
    // --- rest ---
    int*    offs    = (int*)   salloc((size_t)N * 4);
    int*    oend    = (int*)   salloc((size_t)N * 4);
    int*    fcur    = (int*)   salloc(784 * 4);
    int*    ccur    = (int*)   salloc(NC * 4);
    int*    nbr     = (int*)   salloc((size_t)NB * CAPF * 4);        // 9.6 MB (padded fine regions)
    float*  partial = (float*) salloc((size_t)1024 * 256 * 4);       // 1 MB (stats partials)
    __half* pk      = (__half*)salloc((size_t)40960 * 2);            // 80 KB packed weights
    __half* h1h     = (__half*)salloc((size_t)(N + 256) * 32 * 2);   // 6.4 MB
    __half* b1h     = (__half*)salloc((size_t)(N + 256) * 32 * 2);   // 6.4 MB bnrelu(h1)
    __half* h2h     = (__half*)salloc((size_t)(N + 256) * 64 * 2);   // 12.8 MB
    __half* b2h     = (__half*)salloc((size_t)(N + 256) * 64 * 2);   // 12.8 MB bnrelu(h2)
    __half* h3h     = (__half*)salloc((size_t)(N + 256) * 128 * 2);  // 25.7 MB (hosts cpk early)
    __half* aggh    = (__half*)salloc((size_t)(N + 256) * 64 * 2);   // 12.8 MB (hosts qpk early)
    (void)ws_size;

    double* sums1 = sums, *sums2 = sums + 256, *sums3 = sums + 512;
    int* cpk = (int*)h3h;                  // 49*CAPC*4 = 7.2 MB <= 25.7
    int* qpk = (int*)aggh;                 // 782*CAPF*4 = 9.6 MB <= 12.8

    const __half *pwl2h = pk,         *pwl2l = pk + 2048;
    const __half *pwr2h = pk + 4096,  *pwr2l = pk + 6144;
    const __half *pwl3h = pk + 8192,  *pwl3l = pk + 16384;
    const __half *pwr3h = pk + 24576, *pwr3l = pk + 32768;

    hipMemsetAsync(sums, 0, zero_bytes, stream);

    // ---- weight packing + cursor init (fused, tiny) ----
    pack_w<<<80, 256, 0, stream>>>(Wl2, Wr2, Wl3, Wr3, pk, ccur, fcur);

    // ---- CSR build: fixed-capacity buckets, packed 28-bit edge words ----
    part1<<<(E + PT1 - 1) / PT1, 256, 0, stream>>>(dst, src, ccur, cpk, E);
    part2<<<NC * BPC, 256, 0, stream>>>(cpk, ccur, fcur, qpk);
    fill_final<<<NB, 256, 0, stream>>>(qpk, fcur, offs, oend, nbr, N);

    const int NL = (N + 255) / 256;
    const int NBLK = (N + 127) / 128;   // 782 blocks for linear_mfma

    // ---- layer 1: fused agg + linear + stats -> fp16 h1 ----
    layer1_fused<<<NL, 256, 0, stream>>>((const float2*)x, offs, oend, nbr,
                                          Wl1, bl1, Wr1, h1h, sums1, N);

    // ---- layer 2 ----
    bn_apply<32><<<512, 256, 0, stream>>>((const uint4*)h1h, sums1, g1, be1, (uint4*)b1h, N);
    agg_sum<32><<<(N + 63) / 64, dim3(4, 64), 0, stream>>>(
        (const uint4*)b1h, offs, oend, nbr, (uint4*)aggh, N);
    linear_mfma<32, 64><<<NBLK, 256, 0, stream>>>(
        b1h, (const __half*)aggh, pwl2h, pwl2l, pwr2h, pwr2l, bl2, h2h, partial, N);
    stats_finalize2<64><<<128, 256, 0, stream>>>(partial, sums2, NBLK);

    // ---- layer 3 ----
    bn_apply<64><<<512, 256, 0, stream>>>((const uint4*)h2h, sums2, g2, be2, (uint4*)b2h, N);
    agg_sum<64><<<(N + 31) / 32, dim3(8, 32), 0, stream>>>(
        (const uint4*)b2h, offs, oend, nbr, (uint4*)aggh, N);
    linear_mfma<64, 128><<<NBLK, 256, 0, stream>>>(
        b2h, (const __half*)aggh, pwl3h, pwl3l, pwr3h, pwr3l, bl3, h3h, partial, N);
    stats_finalize2<128><<<256, 256, 0, stream>>>(partial, sums3, NBLK);

    // ---- pool + head ----
    pool_partial<<<(N + 63) / 64, 128, 0, stream>>>(h3h, batch, sums3, g3, be3, pooledd, N);
    mlp_fused<<<N_GRAPHS, 128, 0, stream>>>(pooledd, batch, Wf1, bf1, Wf2, bf2, (float*)d_out, N);
}

// Round 13
// 303.376 us; speedup vs baseline: 1.4629x; 1.0132x over previous
//
#include <hip/hip_runtime.h>
#include <hip/hip_fp16.h>

#define N_NODES 100000
#define N_GRAPHS 64
#define BN_EPS 1e-5

#define NBF 391      // fine buckets of 256 nodes
#define PT1 4096
#define CAPF 4608    // per-bucket capacity (mean 4092, sigma~64 -> 8 sigma)

typedef _Float16 f16x8 __attribute__((ext_vector_type(8)));
typedef float f32x4 __attribute__((ext_vector_type(4)));

union F16x8u {
    f16x8 v;
    __half2 h2[4];
    uint4 u;
};

__device__ __forceinline__ float bfly64(float v) {
#pragma unroll
    for (int m = 1; m < 64; m <<= 1) v += __shfl_xor(v, m, 64);
    return v;
}

__device__ __forceinline__ unsigned pack_h2(float a, float b) {
    __half2 h = __floats2half2_rn(a, b);
    unsigned w;
    __builtin_memcpy(&w, &h, 4);
    return w;
}

__device__ __forceinline__ float2 unpack_h2(unsigned w) {
    __half2 h;
    __builtin_memcpy(&h, &w, 4);
    return __half22float2(h);
}

// ---------------- weight packing + cursor init + zero-init (fused) ----------------
// frag[kb][cb][lane][i] holds W[kb*32 + (lane>>4)*8 + i][cb*16 + (lane&15)].
__global__ __launch_bounds__(256)
void pack_w(const float* __restrict__ Wl2, const float* __restrict__ Wr2,
            const float* __restrict__ Wl3, const float* __restrict__ Wr3,
            __half* __restrict__ pk, int* __restrict__ fcur,
            double* __restrict__ zero_region) {
    int tid = threadIdx.x;
    if (blockIdx.x == 0) {
        for (int t = tid; t < NBF; t += 256) fcur[t] = t * CAPF;
    } else if (blockIdx.x <= 4) {
        // zero sums (768 dbl) + pooledd (8192 dbl) = 8960 doubles, contiguous
        for (int i = (blockIdx.x - 1) * 256 + tid; i < 8960; i += 1024)
            zero_region[i] = 0.0;
    }
    int e = blockIdx.x * 256 + tid;   // grid is exactly 80*256 = 20480
    const float* W; int le, DOUT, NCB, base, SZ;
    if (e < 2048)       { W = Wl2; le = e;         DOUT = 64;  NCB = 4; base = 0;     SZ = 2048; }
    else if (e < 4096)  { W = Wr2; le = e - 2048;  DOUT = 64;  NCB = 4; base = 4096;  SZ = 2048; }
    else if (e < 12288) { W = Wl3; le = e - 4096;  DOUT = 128; NCB = 8; base = 8192;  SZ = 8192; }
    else                { W = Wr3; le = e - 12288; DOUT = 128; NCB = 8; base = 24576; SZ = 8192; }
    int i = le & 7;
    int lane = (le >> 3) & 63;
    int cbkb = le >> 9;
    int cb = cbkb % NCB;
    int kb = cbkb / NCB;
    int k = kb * 32 + ((lane >> 4) << 3) + i;
    int col = cb * 16 + (lane & 15);
    float w = W[k * DOUT + col];
    __half h = __float2half(w);
    float lo = w - __half2float(h);
    pk[base + le] = h;
    pk[base + SZ + le] = __float2half(lo);
}

// Packed edge word: bits 0..16 = src (N < 2^17), bits 17..24 = dst & 255.
// Bucket id (dst >> 8) is implied by the region the word lives in.

// ---------------- single-pass partition: edges -> 391 fine buckets ----------------
__global__ __launch_bounds__(256)
void part1(const int* __restrict__ dst, const int* __restrict__ src,
           int* __restrict__ fcur, int* __restrict__ qpk, int E) {
    __shared__ int ld[PT1];
    __shared__ unsigned short lb[PT1];
    __shared__ int hist[NBF], lbase[NBF], gbase[NBF];
    __shared__ int pairs[256];
    long long t0 = (long long)blockIdx.x * PT1;
    int n = (int)min((long long)PT1, (long long)E - t0);
    int tid = threadIdx.x;
    for (int i = tid; i < NBF; i += 256) hist[i] = 0;
    __syncthreads();
    int p[PT1 / 256], c[PT1 / 256];
#pragma unroll
    for (int k = 0; k < PT1 / 256; ++k) {
        int li = k * 256 + tid;
        if (li < n) {
            int d = __builtin_nontemporal_load(dst + t0 + li);
            int s = __builtin_nontemporal_load(src + t0 + li);
            c[k] = d >> 8;
            p[k] = ((d & 255) << 17) | s;
            atomicAdd(&hist[c[k]], 1);
        }
    }
    __syncthreads();
    // exclusive prefix over NBF entries via pair-scan (256 threads, 2 entries each)
    int h0 = (2 * tid < NBF) ? hist[2 * tid] : 0;
    int h1 = (2 * tid + 1 < NBF) ? hist[2 * tid + 1] : 0;
    pairs[tid] = h0 + h1;
    __syncthreads();
    for (int st = 1; st < 256; st <<= 1) {
        int v = (tid >= st) ? pairs[tid - st] : 0;
        __syncthreads();
        pairs[tid] += v;
        __syncthreads();
    }
    int pe = tid ? pairs[tid - 1] : 0;
    if (2 * tid < NBF) lbase[2 * tid] = pe;
    if (2 * tid + 1 < NBF) lbase[2 * tid + 1] = pe + h0;
    __syncthreads();
    for (int b = tid; b < NBF; b += 256)
        gbase[b] = atomicAdd(&fcur[b], hist[b]);
    __syncthreads();
    for (int i = tid; i < NBF; i += 256) hist[i] = 0;
    __syncthreads();
#pragma unroll
    for (int k = 0; k < PT1 / 256; ++k) {
        int li = k * 256 + tid;
        if (li < n) {
            int pos = lbase[c[k]] + atomicAdd(&hist[c[k]], 1);
            ld[pos] = p[k]; lb[pos] = (unsigned short)c[k];
        }
    }
    __syncthreads();
    for (int i = tid; i < n; i += 256) {
        int bb = lb[i];
        int g = gbase[bb] + (i - lbase[bb]);
        qpk[g] = ld[i];
    }
}

// ---------------- per-bucket CSR finalize (256 nodes/bucket; emits beg + end) ----------------
__global__ __launch_bounds__(256)
void fill_final(const int* __restrict__ qpk, const int* __restrict__ fcur,
                int* __restrict__ offs, int* __restrict__ oend,
                int* __restrict__ nbr, int N) {
    __shared__ int cnt[256], cbase[256], cur[256];
    __shared__ int lout[CAPF];
    int b = blockIdx.x;
    int nlo = b << 8;
    int nn = min(256, N - nlo);
    int ebeg = b * CAPF;
    int ne = fcur[b] - ebeg;    // final cursor - base = count
    int tid = threadIdx.x;
    cnt[tid] = 0; cur[tid] = 0;
    __syncthreads();
    for (int i = tid; i < ne; i += 256)
        atomicAdd(&cnt[(qpk[ebeg + i] >> 17) & 255], 1);
    __syncthreads();
    cbase[tid] = cnt[tid];
    __syncthreads();
    for (int st = 1; st < 256; st <<= 1) {
        int v = (tid >= st) ? cbase[tid - st] : 0;
        __syncthreads();
        cbase[tid] += v;
        __syncthreads();
    }
    if (tid < nn) {
        offs[nlo + tid] = ebeg + (tid ? cbase[tid - 1] : 0);
        oend[nlo + tid] = ebeg + cbase[tid];
    }
    __syncthreads();
    for (int i = tid; i < ne; i += 256) {
        int p = qpk[ebeg + i];
        int ln = (p >> 17) & 255;
        int pos = (ln ? cbase[ln - 1] : 0) + atomicAdd(&cur[ln], 1);
        lout[pos] = p & 0x1FFFF;
    }
    __syncthreads();
    for (int i = tid; i < ne; i += 256)
        nbr[ebeg + i] = lout[i];
}

// ---------------- layer 1 fused: agg + linear + BN stats; fp16 h1 out ----------------
__global__ __launch_bounds__(256)
void layer1_fused(const float2* __restrict__ x2,
                  const int* __restrict__ offs, const int* __restrict__ oend,
                  const int* __restrict__ nbr,
                  const float* __restrict__ Wl, const float* __restrict__ bl,
                  const float* __restrict__ Wr,
                  __half* __restrict__ hout16,
                  double* __restrict__ sums, int N) {
    __shared__ float sAr[64];
    int tid = threadIdx.x;
    if (tid < 64) sAr[tid] = 0.f;
    __syncthreads();
    int n = blockIdx.x * 256 + tid;
    bool valid = (n < N);
    int beg = 0, end = 0;
    if (valid) { beg = offs[n]; end = oend[n]; }
    float ax0 = 0.f, ay0 = 0.f, ax1 = 0.f, ay1 = 0.f;
    int j = beg;
    for (; j + 16 <= end; j += 16) {
        int s[16];
#pragma unroll
        for (int u = 0; u < 16; ++u) s[u] = __builtin_nontemporal_load(nbr + j + u);
        float2 v[16];
#pragma unroll
        for (int u = 0; u < 16; ++u) v[u] = x2[s[u]];
#pragma unroll
        for (int u = 0; u < 16; ++u) {
            if (u & 1) { ax1 += v[u].x; ay1 += v[u].y; }
            else       { ax0 += v[u].x; ay0 += v[u].y; }
        }
    }
    for (; j + 4 <= end; j += 4) {
        int s[4];
#pragma unroll
        for (int u = 0; u < 4; ++u) s[u] = __builtin_nontemporal_load(nbr + j + u);
        float2 v[4];
#pragma unroll
        for (int u = 0; u < 4; ++u) v[u] = x2[s[u]];
        ax0 += v[0].x; ay0 += v[0].y;
        ax1 += v[1].x; ay1 += v[1].y;
        ax0 += v[2].x; ay0 += v[2].y;
        ax1 += v[3].x; ay1 += v[3].y;
    }
    for (; j < end; ++j) {
        float2 v = x2[nbr[j]];
        ax0 += v.x; ay0 += v.y;
    }
    float invd = 1.0f / fmaxf((float)(end - beg), 1.0f);
    float a0 = (ax0 + ax1) * invd, a1 = (ay0 + ay1) * invd;
    float x0 = 0.f, x1 = 0.f;
    if (valid) {
        float2 xv = x2[n];
        x0 = xv.x; x1 = xv.y;
    }
    float acc[32];
#pragma unroll
    for (int jj = 0; jj < 32; ++jj)
        acc[jj] = bl[jj] + a0 * Wl[jj] + a1 * Wl[32 + jj] + x0 * Wr[jj] + x1 * Wr[32 + jj];
    if (valid) {
        unsigned w[16];
#pragma unroll
        for (int p = 0; p < 16; ++p) w[p] = pack_h2(acc[2*p], acc[2*p+1]);
        uint4* q = (uint4*)(hout16 + (size_t)n * 32);
        q[0] = make_uint4(w[0], w[1], w[2], w[3]);
        q[1] = make_uint4(w[4], w[5], w[6], w[7]);
        q[2] = make_uint4(w[8], w[9], w[10], w[11]);
        q[3] = make_uint4(w[12], w[13], w[14], w[15]);
    }
    int lane = tid & 63;
#pragma unroll
    for (int jj = 0; jj < 32; ++jj) {
        float v = valid ? acc[jj] : 0.f;
        float s = bfly64(v);
        float q = bfly64(v * v);
        if (lane == jj) atomicAdd(&sAr[jj], s);
        if (lane == 32 + jj) atomicAdd(&sAr[32 + jj], q);
    }
    __syncthreads();
    if (tid < 64) atomicAdd(&sums[tid], (double)sAr[tid]);
}

// ---------------- per-node BN+ReLU apply: h -> b (fp16), once per node ----------------
template<int F>
__global__ __launch_bounds__(256)
void bn_apply(const uint4* __restrict__ h, const double* __restrict__ sums,
              const float* __restrict__ gamma, const float* __restrict__ beta,
              uint4* __restrict__ out, int N) {
    __shared__ __align__(16) float lsc[F], lsf[F];
    int tid = threadIdx.x;
    if (tid < F) {
        double mu = sums[tid] / (double)N_NODES;
        double var = sums[F + tid] / (double)N_NODES - mu * mu;
        if (var < 0.0) var = 0.0;
        double sc = (double)gamma[tid] / sqrt(var + BN_EPS);
        lsc[tid] = (float)sc;
        lsf[tid] = (float)((double)beta[tid] - mu * sc);
    }
    __syncthreads();
    constexpr int FV = F / 8;
    int total = N * FV;
    for (int i = blockIdx.x * 256 + tid; i < total; i += gridDim.x * 256) {
        uint4 v = h[i];
        int c4 = (i & (FV - 1)) * 2;      // float4 index of first quad
        float4 sca = ((const float4*)lsc)[c4];
        float4 scb = ((const float4*)lsc)[c4 + 1];
        float4 sfa = ((const float4*)lsf)[c4];
        float4 sfb = ((const float4*)lsf)[c4 + 1];
        float2 f0 = unpack_h2(v.x), f1 = unpack_h2(v.y);
        float2 f2 = unpack_h2(v.z), f3 = unpack_h2(v.w);
        uint4 o;
        o.x = pack_h2(fmaxf(f0.x * sca.x + sfa.x, 0.f), fmaxf(f0.y * sca.y + sfa.y, 0.f));
        o.y = pack_h2(fmaxf(f1.x * sca.z + sfa.z, 0.f), fmaxf(f1.y * sca.w + sfa.w, 0.f));
        o.z = pack_h2(fmaxf(f2.x * scb.x + sfb.x, 0.f), fmaxf(f2.y * scb.y + sfb.y, 0.f));
        o.w = pack_h2(fmaxf(f3.x * scb.z + sfb.z, 0.f), fmaxf(f3.y * scb.w + sfb.w, 0.f));
        out[i] = o;
    }
}

// ---------------- fp16 sum-gather agg, 16-deep MLP, fp32 dual-bank accum ----------------
__device__ __forceinline__ void accum8_h16(float* acc, uint4 v) {
    float2 f0 = unpack_h2(v.x), f1 = unpack_h2(v.y);
    float2 f2 = unpack_h2(v.z), f3 = unpack_h2(v.w);
    acc[0] += f0.x; acc[1] += f0.y; acc[2] += f1.x; acc[3] += f1.y;
    acc[4] += f2.x; acc[5] += f2.y; acc[6] += f3.x; acc[7] += f3.y;
}

template<int F>
__global__ __launch_bounds__(256)
void agg_sum(const uint4* __restrict__ xb, const int* __restrict__ offs,
             const int* __restrict__ oend, const int* __restrict__ nbr,
             uint4* __restrict__ aggh, int N) {
    constexpr int FV = F / 8;            // uint4 lanes per row
    constexpr int NPB = 256 / FV;        // nodes per block
    int n = blockIdx.x * NPB + threadIdx.y;
    if (n >= N) return;
    int f = threadIdx.x;
    int beg = offs[n], end = oend[n];
    float a0[8], a1[8];
#pragma unroll
    for (int q = 0; q < 8; ++q) { a0[q] = 0.f; a1[q] = 0.f; }
    int j = beg;
    // 16-deep main loop: 16 independent gathers in flight per thread
    for (; j + 16 <= end; j += 16) {
        int s[16];
#pragma unroll
        for (int u = 0; u < 16; ++u) s[u] = __builtin_nontemporal_load(nbr + j + u);
        uint4 v[16];
#pragma unroll
        for (int u = 0; u < 16; ++u) v[u] = xb[s[u] * FV + f];
#pragma unroll
        for (int u = 0; u < 16; ++u)
            accum8_h16((u & 1) ? a1 : a0, v[u]);
    }
    if (j + 8 <= end) {
        int s[8];
#pragma unroll
        for (int u = 0; u < 8; ++u) s[u] = __builtin_nontemporal_load(nbr + j + u);
        uint4 v[8];
#pragma unroll
        for (int u = 0; u < 8; ++u) v[u] = xb[s[u] * FV + f];
#pragma unroll
        for (int u = 0; u < 8; ++u)
            accum8_h16((u & 1) ? a1 : a0, v[u]);
        j += 8;
    }
    if (j + 4 <= end) {
        int s[4];
#pragma unroll
        for (int u = 0; u < 4; ++u) s[u] = __builtin_nontemporal_load(nbr + j + u);
        uint4 v[4];
#pragma unroll
        for (int u = 0; u < 4; ++u) v[u] = xb[s[u] * FV + f];
#pragma unroll
        for (int u = 0; u < 4; ++u)
            accum8_h16((u & 1) ? a1 : a0, v[u]);
        j += 4;
    }
    for (; j < end; ++j) {
        uint4 v = xb[__builtin_nontemporal_load(nbr + j) * FV + f];
        accum8_h16(a0, v);
    }
    float invd = 1.0f / fmaxf((float)(end - beg), 1.0f);
    uint4 o;
    o.x = pack_h2((a0[0] + a1[0]) * invd, (a0[1] + a1[1]) * invd);
    o.y = pack_h2((a0[2] + a1[2]) * invd, (a0[3] + a1[3]) * invd);
    o.z = pack_h2((a0[4] + a1[4]) * invd, (a0[5] + a1[5]) * invd);
    o.w = pack_h2((a0[6] + a1[6]) * invd, (a0[7] + a1[7]) * invd);
    aggh[n * FV + f] = o;
}

// ---------------- MFMA linear: pure-load fp16 fragments (agg pre-scaled, x pre-BN'd),
// split-fp16 weights, fp32 MFMA accumulate, fp16 out, fused BN-stats partials ----------------
template<int DIN, int DOUT>
__global__ __launch_bounds__(256)
void linear_mfma(const __half* __restrict__ bnx16, const __half* __restrict__ agg16,
                 const __half* __restrict__ wlhi, const __half* __restrict__ wllo,
                 const __half* __restrict__ wrhi, const __half* __restrict__ wrlo,
                 const float* __restrict__ bl,
                 __half* __restrict__ hout16, float* __restrict__ partial, int N) {
    constexpr int KB = DIN / 32;    // K-slabs of 32
    constexpr int NCB = DOUT / 16;  // col-blocks of 16
    constexpr int MREP = 2;         // 16-row fragments per wave
    constexpr int MB = 4 * MREP * 16;  // 128 rows per block
    __shared__ float blkS[DOUT], blkQ[DOUT];
    int tid = threadIdx.x;
    for (int i = tid; i < DOUT; i += 256) { blkS[i] = 0.f; blkQ[i] = 0.f; }
    __syncthreads();
    int n0 = blockIdx.x * MB;

    int wave = tid >> 6;
    int lane = tid & 63;
    int rlane = lane & 15;
    int kg = lane >> 4;          // 0..3 -> k-group of 8
    int rbase = n0 + wave * (MREP * 16);

    // ---- A fragments: pure vector loads ----
    f16x8 aA[MREP][KB], aX[MREP][KB];
#pragma unroll
    for (int m = 0; m < MREP; ++m) {
        int row = rbase + m * 16 + rlane;
        int rowc = min(row, N - 1);
#pragma unroll
        for (int kb = 0; kb < KB; ++kb) {
            int c0 = kb * 32 + kg * 8;
            F16x8u ta, tx;
            ta.u = *(const uint4*)(agg16 + (size_t)rowc * DIN + c0);
            tx.u = *(const uint4*)(bnx16 + (size_t)rowc * DIN + c0);
            aA[m][kb] = ta.v;
            aX[m][kb] = tx.v;
        }
    }

    // ---- accumulators init with bias (D layout: row=(lane>>4)*4+r, col=lane&15) ----
    f32x4 acc[MREP][NCB];
#pragma unroll
    for (int cb = 0; cb < NCB; ++cb) {
        float bv = bl[cb * 16 + rlane];
#pragma unroll
        for (int m = 0; m < MREP; ++m)
            acc[m][cb] = {bv, bv, bv, bv};
    }

    // ---- MFMA main: acc += aA*(Wl_hi+Wl_lo) + aX*(Wr_hi+Wr_lo) ----
#pragma unroll
    for (int cb = 0; cb < NCB; ++cb) {
#pragma unroll
        for (int kb = 0; kb < KB; ++kb) {
            size_t fo = ((size_t)(kb * NCB + cb) * 64 + lane) * 8;
            f16x8 blh = *(const f16x8*)(wlhi + fo);
            f16x8 bll = *(const f16x8*)(wllo + fo);
            f16x8 brh = *(const f16x8*)(wrhi + fo);
            f16x8 brl = *(const f16x8*)(wrlo + fo);
#pragma unroll
            for (int m = 0; m < MREP; ++m) {
                acc[m][cb] = __builtin_amdgcn_mfma_f32_16x16x32_f16(aA[m][kb], blh, acc[m][cb], 0, 0, 0);
                acc[m][cb] = __builtin_amdgcn_mfma_f32_16x16x32_f16(aA[m][kb], bll, acc[m][cb], 0, 0, 0);
                acc[m][cb] = __builtin_amdgcn_mfma_f32_16x16x32_f16(aX[m][kb], brh, acc[m][cb], 0, 0, 0);
                acc[m][cb] = __builtin_amdgcn_mfma_f32_16x16x32_f16(aX[m][kb], brl, acc[m][cb], 0, 0, 0);
            }
        }
    }

    // ---- store fp16 outputs ----
#pragma unroll
    for (int m = 0; m < MREP; ++m) {
        int rowb = rbase + m * 16 + kg * 4;
#pragma unroll
        for (int r = 0; r < 4; ++r) {
            int node = rowb + r;
            if (node < N) {
#pragma unroll
                for (int cb = 0; cb < NCB; ++cb)
                    hout16[(size_t)node * DOUT + cb * 16 + rlane] = __float2half(acc[m][cb][r]);
            }
        }
    }

    // ---- fused BN-stats partials: per-block sum/sumsq per feature ----
#pragma unroll
    for (int cb = 0; cb < NCB; ++cb) {
        float s = 0.f, q = 0.f;
#pragma unroll
        for (int m = 0; m < MREP; ++m) {
            int rowb = rbase + m * 16 + kg * 4;
#pragma unroll
            for (int r = 0; r < 4; ++r) {
                if (rowb + r < N) {
                    float v = acc[m][cb][r];
                    s += v; q += v * v;
                }
            }
        }
        s += __shfl_xor(s, 16, 64); s += __shfl_xor(s, 32, 64);
        q += __shfl_xor(q, 16, 64); q += __shfl_xor(q, 32, 64);
        if (kg == 0) {
            atomicAdd(&blkS[cb * 16 + rlane], s);
            atomicAdd(&blkQ[cb * 16 + rlane], q);
        }
    }
    __syncthreads();
    float* po = partial + (size_t)blockIdx.x * (2 * DOUT);
    for (int i = tid; i < DOUT; i += 256) {
        po[i] = blkS[i];
        po[DOUT + i] = blkQ[i];
    }
}

// ---------------- stats finalize: reduce P block-partials per feature in fp64, fixed order ----------------
template<int F>
__global__ __launch_bounds__(256)
void stats_finalize2(const float* __restrict__ partial, double* __restrict__ sums, int P) {
    __shared__ double sh[256];
    int i = blockIdx.x;
    int t = threadIdx.x;
    double a = 0.0;
    for (int k = t; k < P; k += 256)
        a += (double)partial[(size_t)k * (2 * F) + i];
    sh[t] = a;
    __syncthreads();
    for (int st = 128; st > 0; st >>= 1) {
        if (t < st) sh[t] += sh[t + st];
        __syncthreads();
    }
    if (t == 0) sums[i] = sh[0];
}

// ---------------- pool (fp16 h3) with inline BN3 finalize + fused ReLU ----------------
__global__ void pool_partial(const __half* __restrict__ h, const int* __restrict__ batch,
                             const double* __restrict__ sums,
                             const float* __restrict__ gamma, const float* __restrict__ beta,
                             double* __restrict__ pooled_d, int N) {
    __shared__ float lsc[128], lsf[128];
    const int CH = 64;
    int f = threadIdx.x;
    {
        double mu = sums[f] / (double)N_NODES;
        double var = sums[128 + f] / (double)N_NODES - mu * mu;
        if (var < 0.0) var = 0.0;
        double sc = (double)gamma[f] / sqrt(var + BN_EPS);
        lsc[f] = (float)sc;
        lsf[f] = (float)((double)beta[f] - mu * sc);
    }
    __syncthreads();
    int n0 = blockIdx.x * CH;
    if (n0 >= N) return;
    int n1 = min(n0 + CH, N);
    float sc = lsc[f], sf = lsf[f];
    int g = batch[n0];
    float acc = 0.f;
    for (int n = n0; n < n1; ++n) {
        int bg = batch[n];
        if (bg != g) {
            atomicAdd(&pooled_d[g * 128 + f], (double)acc);
            acc = 0.f;
            g = bg;
        }
        float v = __half2float(h[(long long)n * 128 + f]);
        acc += fmaxf(v * sc + sf, 0.f);
    }
    atomicAdd(&pooled_d[g * 128 + f], (double)acc);
}

// ---------------- fused pool-finalize + head MLP ----------------
__global__ void mlp_fused(const double* __restrict__ pooled_d, const int* __restrict__ batch,
                          const float* __restrict__ Wf1, const float* __restrict__ bf1,
                          const float* __restrict__ Wf2, const float* __restrict__ bf2,
                          float* __restrict__ out, int N) {
    __shared__ float sp[128];
    int g = blockIdx.x;
    int t = threadIdx.x;
    int lo = 0, hi = N;
    while (lo < hi) { int m = (lo + hi) >> 1; if (batch[m] < g) lo = m + 1; else hi = m; }
    int start = lo;
    hi = N;
    while (lo < hi) { int m = (lo + hi) >> 1; if (batch[m] < g + 1) lo = m + 1; else hi = m; }
    int cnt = lo - start;
    sp[t] = (float)(pooled_d[g * 128 + t] / (double)max(cnt, 1));
    __syncthreads();
    if (t < 64) {
        float hacc = bf1[t];
#pragma unroll 8
        for (int k = 0; k < 128; ++k) hacc += sp[k] * Wf1[k * 64 + t];
        hacc = fmaxf(hacc, 0.f) * Wf2[t];
        for (int o = 32; o > 0; o >>= 1) hacc += __shfl_down(hacc, o);
        if (t == 0) out[g] = hacc + bf2[0];
    }
}

extern "C" void kernel_launch(void* const* d_in, const int* in_sizes, int n_in,
                              void* d_out, int out_size, void* d_ws, size_t ws_size,
                              hipStream_t stream) {
    const float* x     = (const float*)d_in[0];
    const int*   ei    = (const int*)d_in[1];
    const int*   batch = (const int*)d_in[2];
    const float *Wl1=(const float*)d_in[3],  *bl1=(const float*)d_in[4],  *Wr1=(const float*)d_in[5];
    const float *g1 =(const float*)d_in[6],  *be1=(const float*)d_in[7];
    const float *Wl2=(const float*)d_in[8],  *bl2=(const float*)d_in[9],  *Wr2=(const float*)d_in[10];
    const float *g2 =(const float*)d_in[11], *be2=(const float*)d_in[12];
    const float *Wl3=(const float*)d_in[13], *bl3=(const float*)d_in[14], *Wr3=(const float*)d_in[15];
    const float *g3 =(const float*)d_in[16], *be3=(const float*)d_in[17];
    const float *Wf1=(const float*)d_in[18], *bf1=(const float*)d_in[19];
    const float *Wf2=(const float*)d_in[20], *bf2=(const float*)d_in[21];

    const int N = N_NODES;
    const int E = in_sizes[1] / 2;
    const int* src = ei;
    const int* dst = ei + E;

    char* ws = (char*)d_ws;
    size_t off = 0;
    auto salloc = [&](size_t bytes) {
        void* p = ws + off;
        off += (bytes + 255) & ~(size_t)255;
        return p;
    };
    // --- zeroed-in-pack_w region (must stay contiguous: sums then pooledd) ---
    double* sums    = (double*)salloc(768 * 8);                      // 6144 B (256-aligned)
    double* pooledd = (double*)salloc((size_t)N_GRAPHS * 128 * 8);   // 65536 B
    // --- rest ---
    int*    offs    = (int*)   salloc((size_t)N * 4);
    int*    oend    = (int*)   salloc((size_t)N * 4);
    int*    fcur    = (int*)   salloc((NBF + 1) * 4);
    int*    nbr     = (int*)   salloc((size_t)NBF * CAPF * 4);       // 7.2 MB (padded bucket regions)
    float*  partial = (float*) salloc((size_t)1024 * 256 * 4);       // 1 MB (stats partials)
    __half* pk      = (__half*)salloc((size_t)40960 * 2);            // 80 KB packed weights
    __half* h1h     = (__half*)salloc((size_t)(N + 256) * 32 * 2);   // 6.4 MB
    __half* b1h     = (__half*)salloc((size_t)(N + 256) * 32 * 2);   // 6.4 MB bnrelu(h1)
    __half* h2h     = (__half*)salloc((size_t)(N + 256) * 64 * 2);   // 12.8 MB
    __half* b2h     = (__half*)salloc((size_t)(N + 256) * 64 * 2);   // 12.8 MB bnrelu(h2)
    __half* h3h     = (__half*)salloc((size_t)(N + 256) * 128 * 2);  // 25.7 MB
    __half* aggh    = (__half*)salloc((size_t)(N + 256) * 64 * 2);   // 12.8 MB (hosts qpk early)
    (void)ws_size;

    double* sums1 = sums, *sums2 = sums + 256, *sums3 = sums + 512;
    int* qpk = (int*)aggh;                 // 391*CAPF*4 = 7.2 MB <= 12.8

    const __half *pwl2h = pk,         *pwl2l = pk + 2048;
    const __half *pwr2h = pk + 4096,  *pwr2l = pk + 6144;
    const __half *pwl3h = pk + 8192,  *pwl3l = pk + 16384;
    const __half *pwr3h = pk + 24576, *pwr3l = pk + 32768;

    // ---- weight packing + cursor init + zero-init (fused, tiny) ----
    pack_w<<<80, 256, 0, stream>>>(Wl2, Wr2, Wl3, Wr3, pk, fcur, sums);

    // ---- CSR build: single-pass partition into 391 fixed-capacity buckets ----
    part1<<<(E + PT1 - 1) / PT1, 256, 0, stream>>>(dst, src, fcur, qpk, E);
    fill_final<<<NBF, 256, 0, stream>>>(qpk, fcur, offs, oend, nbr, N);

    const int NL = (N + 255) / 256;
    const int NBLK = (N + 127) / 128;   // 782 blocks for linear_mfma

    // ---- layer 1: fused agg + linear + stats -> fp16 h1 ----
    layer1_fused<<<NL, 256, 0, stream>>>((const float2*)x, offs, oend, nbr,
                                          Wl1, bl1, Wr1, h1h, sums1, N);

    // ---- layer 2 ----
    bn_apply<32><<<512, 256, 0, stream>>>((const uint4*)h1h, sums1, g1, be1, (uint4*)b1h, N);
    agg_sum<32><<<(N + 63) / 64, dim3(4, 64), 0, stream>>>(
        (const uint4*)b1h, offs, oend, nbr, (uint4*)aggh, N);
    linear_mfma<32, 64><<<NBLK, 256, 0, stream>>>(
        b1h, (const __half*)aggh, pwl2h, pwl2l, pwr2h, pwr2l, bl2, h2h, partial, N);
    stats_finalize2<64><<<128, 256, 0, stream>>>(partial, sums2, NBLK);

    // ---- layer 3 ----
    bn_apply<64><<<512, 256, 0, stream>>>((const uint4*)h2h, sums2, g2, be2, (uint4*)b2h, N);
    agg_sum<64><<<(N + 31) / 32, dim3(8, 32), 0, stream>>>(
        (const uint4*)b2h, offs, oend, nbr, (uint4*)aggh, N);
    linear_mfma<64, 128><<<NBLK, 256, 0, stream>>>(
        b2h, (const __half*)aggh, pwl3h, pwl3l, pwr3h, pwr3l, bl3, h3h, partial, N);
    stats_finalize2<128><<<256, 256, 0, stream>>>(partial, sums3, NBLK);

    // ---- pool + head ----
    pool_partial<<<(N + 63) / 64, 128, 0, stream>>>(h3h, batch, sums3, g3, be3, pooledd, N);
    mlp_fused<<<N_GRAPHS, 128, 0, stream>>>(pooledd, batch, Wf1, bf1, Wf2, bf2, (float*)d_out, N);
}